// Round 13
// baseline (70.669 us; speedup 1.0000x reference)
//
#include <hip/hip_runtime.h>
#include <hip/hip_bf16.h>

#define BB 4
#define TT 4096
#define DM 1024
#define DK 64
#define NSPLIT 8

using f32x4  = __attribute__((ext_vector_type(4))) float;
using bf16x8 = __attribute__((ext_vector_type(8))) short;

__device__ __forceinline__ short f2bf(float f) {
    __hip_bfloat16 h = __float2bfloat16(f);
    return __builtin_bit_cast(short, h);
}
__device__ __forceinline__ float bf2f(short s) {
    unsigned int u = ((unsigned int)(unsigned short)s) << 16;
    return __builtin_bit_cast(float, u);
}

// ---------------- Kernel 0: pack Wq|Wk|Wv (f32 [1024][64]) -> Wt bf16 [192][1024]
__global__ __launch_bounds__(256) void wt_kernel(const float* __restrict__ Wq,
                                                 const float* __restrict__ Wk,
                                                 const float* __restrict__ Wv,
                                                 short* __restrict__ Wt) {
    int idx = blockIdx.x * 256 + threadIdx.x;
    if (idx >= 192 * 1024) return;
    int n = idx >> 10;
    int m = idx & 1023;
    const float* W = (n < 64) ? Wq : (n < 128) ? Wk : Wv;
    int c = n & 63;
    Wt[idx] = f2bf(W[m * 64 + c]);
}

// ---------------- Kernel 1: QKV projection GEMM (R9 config: BM=64, 256 thr, bf16 LDS)
// q is pre-scaled by 1/8 (folded attention scale).
__global__ __launch_bounds__(256, 4) void proj_rope(const float* __restrict__ x,
                                                    const float* __restrict__ freqs,
                                                    const short* __restrict__ Wt,
                                                    short* __restrict__ q,
                                                    short* __restrict__ k,
                                                    short* __restrict__ vt)
{
    __shared__ short As[2][4096];    // [64 rows][8 units of 16B], unit-XOR-swizzled
    __shared__ short Bs[2][4096];

    int t  = threadIdx.x;
    int w  = t >> 6;
    int l  = t & 63;
    int lr = l & 15;
    int lg = (l >> 4) & 3;
    int bx = blockIdx.x;
    int mt = (bx & 7) * 32 + (bx >> 3) / 3;   // trio-per-XCD
    int nh = (bx >> 3) % 3;                   // 0=q, 1=k, 2=v
    int m0 = mt * 64;

    int arow = t >> 2;
    int au2  = (t & 3) * 2;
    int aswz = arow & 7;
    const float* gA = x  + (size_t)(m0 + arow) * DM + au2 * 8;
    const short* gB = Wt + (size_t)(nh * 64 + arow) * DM + au2 * 8;

    f32x4 ar[4]; bf16x8 br[2];

#define LOADG(c_) do { int kk = (c_) << 6;                     \
        ar[0] = *(const f32x4*)(gA + kk);                      \
        ar[1] = *(const f32x4*)(gA + kk + 4);                  \
        ar[2] = *(const f32x4*)(gA + kk + 8);                  \
        ar[3] = *(const f32x4*)(gA + kk + 12);                 \
        br[0] = *(const bf16x8*)(gB + kk);                     \
        br[1] = *(const bf16x8*)(gB + kk + 8);                 \
    } while (0)

#define WRITELDS(buf_) do {                                                    \
        int sa = arow * 64;                                                    \
        bf16x8 a0_, a1_;                                                       \
        for (int j_ = 0; j_ < 4; ++j_) {                                       \
            a0_[j_] = f2bf(ar[0][j_]); a0_[4 + j_] = f2bf(ar[1][j_]);          \
            a1_[j_] = f2bf(ar[2][j_]); a1_[4 + j_] = f2bf(ar[3][j_]);          \
        }                                                                      \
        *(bf16x8*)&As[buf_][sa + (((au2    ) ^ aswz) << 3)] = a0_;             \
        *(bf16x8*)&As[buf_][sa + (((au2 + 1) ^ aswz) << 3)] = a1_;             \
        *(bf16x8*)&Bs[buf_][sa + (((au2    ) ^ aswz) << 3)] = br[0];           \
        *(bf16x8*)&Bs[buf_][sa + (((au2 + 1) ^ aswz) << 3)] = br[1];           \
    } while (0)

    f32x4 acc[4];
#pragma unroll
    for (int i = 0; i < 4; ++i) acc[i] = (f32x4){0.f, 0.f, 0.f, 0.f};

    LOADG(0); WRITELDS(0); LOADG(1);
    __syncthreads();

    int cur = 0;
    int r7 = lr & 7;
    int amrow = (w * 16 + lr) * 64;
    for (int ch = 0; ch < 16; ++ch) {
#pragma unroll
        for (int s = 0; s < 2; ++s) {
            int u0 = s * 4 + lg;
            bf16x8 af = *(const bf16x8*)&As[cur][amrow + ((u0 ^ r7) << 3)];
#pragma unroll
            for (int nt = 0; nt < 4; ++nt) {
                bf16x8 bfr = *(const bf16x8*)&Bs[cur][(nt * 16 + lr) * 64 + ((u0 ^ r7) << 3)];
                acc[nt] = __builtin_amdgcn_mfma_f32_16x16x32_bf16(af, bfr, acc[nt], 0, 0, 0);
            }
        }
        if (ch + 1 < 16) {
            WRITELDS(cur ^ 1);
            if (ch + 2 < 16) LOADG(ch + 2);
            __syncthreads();
            cur ^= 1;
        }
    }
#undef LOADG
#undef WRITELDS

    __syncthreads();

    if (nh == 2) {
        short* vs = &Bs[0][0];
#pragma unroll
        for (int r = 0; r < 4; ++r)
#pragma unroll
            for (int nt = 0; nt < 4; ++nt)
                vs[(w * 16 + lg * 4 + r) * 64 + nt * 16 + lr] = f2bf(acc[nt][r]);
        __syncthreads();
        int b   = mt >> 6;
        int tt0 = (mt & 63) * 64;
        int c   = t >> 2;
        int toff = (t & 3) * 16;
        bf16x8 v0, v1;
#pragma unroll
        for (int j = 0; j < 8; ++j) {
            v0[j] = vs[(toff + j) * 64 + c];
            v1[j] = vs[(toff + 8 + j) * 64 + c];
        }
        short* dstv = vt + ((size_t)b * DK + c) * TT + tt0 + toff;
        *(bf16x8*)dstv = v0;
        *(bf16x8*)(dstv + 8) = v1;
    } else {
        short* dst = nh ? k : q;
        float postscale = nh ? 1.0f : 0.125f;      // fold S-scale into q
#pragma unroll
        for (int r = 0; r < 4; ++r) {
            int tg = m0 + w * 16 + lg * 4 + r;
            int tt = tg & (TT - 1);
#pragma unroll
            for (int nt = 0; nt < 4; ++nt) {
                int c = nt * 16 + lr;
                float e = acc[nt][r];
                float p = __shfl_xor(e, 1);
                float2 f = ((const float2*)freqs)[(size_t)tt * 32 + (c >> 1)];
                float sgn = (c & 1) ? f.y : -f.y;
                dst[(size_t)tg * DK + c] = f2bf((e * f.x + p * sgn) * postscale);
            }
        }
    }
}

// ---------------- Kernel 2: causal flash attention, q-tile 128 (2 row-groups/wave)
// R8 staging structure (single-buffer 25.6 KB, 1-deep reg prefetch, (256,4)) but each
// staged K/V tile feeds TWO 16-row groups per wave -> staging traffic, barriers and
// block count per unit work halve. po/ml stay indexed by 64-row tiles (merge unchanged).
__global__ __launch_bounds__(256, 4) void attn_kernel(const short* __restrict__ q,
                                                      const short* __restrict__ k,
                                                      const short* __restrict__ vt,
                                                      short* __restrict__ po,
                                                      float* __restrict__ ml)
{
    __shared__ short Kb[64][64];
    __shared__ short Vb[64][64];
    __shared__ short pbuf[4][16][72];

    int w  = threadIdx.x >> 6;
    int l  = threadIdx.x & 63;
    int lr = l & 15;
    int lg = l >> 4;
    int b  = blockIdx.y;
    int s  = blockIdx.z;
    int qt = 31 - blockIdx.x;           // 128-row q-tiles, heavy first
    int q0 = qt * 128;

    const short* qB = q  + (size_t)b * TT * DK;
    const short* kB = k  + (size_t)b * TT * DK;
    const short* vB = vt + (size_t)b * DK * TT;

    bf16x8 qf[2][2];
#pragma unroll
    for (int rg = 0; rg < 2; ++rg) {
        int qrow = q0 + rg * 64 + w * 16;
        qf[rg][0] = *(const bf16x8*)(qB + (size_t)(qrow + lr) * DK + 8 * lg);
        qf[rg][1] = *(const bf16x8*)(qB + (size_t)(qrow + lr) * DK + 32 + 8 * lg);
    }

    f32x4 of[2][4];
    float m[2][4], lsum[2][4];
#pragma unroll
    for (int rg = 0; rg < 2; ++rg)
#pragma unroll
        for (int r = 0; r < 4; ++r) {
            of[rg][r] = (f32x4){0.f, 0.f, 0.f, 0.f};
            m[rg][r] = -INFINITY; lsum[rg][r] = 0.f;
        }

    int ntot = 2 * qt + 2;                       // 64-wide kv tiles covering this q-tile
    int nt   = (s < ntot) ? (((ntot - 1 - s) >> 3) + 1) : 0;

    int srow = threadIdx.x >> 2;
    int u0   = (threadIdx.x & 3) * 2;
    int p0s  = ((u0) ^ (srow & 7)) * 8;
    int p1s  = ((u0 + 1) ^ (srow & 7)) * 8;

    bf16x8 kr0, kr1, vr0, vr1;
    short* mypb = &pbuf[w][0][0];

#define ISSUE(tile_) do {                                                        \
        int kv0_ = (tile_) << 6;                                                 \
        const short* gk_ = kB + (size_t)(kv0_ + srow) * DK + (u0 * 8);           \
        const short* gv_ = vB + (size_t)srow * TT + kv0_ + (u0 * 8);             \
        kr0 = *(const bf16x8*)gk_; kr1 = *(const bf16x8*)(gk_ + 8);              \
        vr0 = *(const bf16x8*)gv_; vr1 = *(const bf16x8*)(gv_ + 8);              \
    } while (0)

#define WRITE() do {                                                             \
        *(bf16x8*)&Kb[srow][p0s] = kr0;                                         \
        *(bf16x8*)&Kb[srow][p1s] = kr1;                                         \
        *(bf16x8*)&Vb[srow][p0s] = vr0;                                         \
        *(bf16x8*)&Vb[srow][p1s] = vr1;                                         \
    } while (0)

    if (nt > 0) {
        ISSUE(s); WRITE();
        if (nt > 1) ISSUE(s + NSPLIT);
        __syncthreads();
        for (int i = 0; i < nt; ++i) {
            int kv0 = (s + i * NSPLIT) << 6;

#pragma unroll
            for (int rg = 0; rg < 2; ++rg) {
                int qbase = q0 + rg * 64;            // block-uniform gate
                if (kv0 <= qbase) {
                    int qrow_wave = qbase + w * 16;

                    // ---- QK^T
                    f32x4 sc[4];
#pragma unroll
                    for (int c = 0; c < 4; ++c) sc[c] = (f32x4){0.f, 0.f, 0.f, 0.f};
#pragma unroll
                    for (int c = 0; c < 4; ++c) {
                        int row = c * 16 + lr;
                        bf16x8 kf0 = *(const bf16x8*)&Kb[row][((lg) ^ (row & 7)) * 8];
                        bf16x8 kf1 = *(const bf16x8*)&Kb[row][((4 + lg) ^ (row & 7)) * 8];
                        sc[c] = __builtin_amdgcn_mfma_f32_16x16x32_bf16(qf[rg][0], kf0, sc[c], 0, 0, 0);
                        sc[c] = __builtin_amdgcn_mfma_f32_16x16x32_bf16(qf[rg][1], kf1, sc[c], 0, 0, 0);
                    }

                    // ---- mask only on this row-group's diagonal tile
                    if (kv0 == qbase) {
#pragma unroll
                        for (int r = 0; r < 4; ++r) {
                            int qg = qrow_wave + lg * 4 + r;
#pragma unroll
                            for (int c = 0; c < 4; ++c)
                                sc[c][r] = (kv0 + c * 16 + lr <= qg) ? sc[c][r] : -INFINITY;
                        }
                    }

                    // ---- local per-lane row max; gate the expensive path
                    float mx[4];
#pragma unroll
                    for (int r = 0; r < 4; ++r)
                        mx[r] = fmaxf(fmaxf(sc[0][r], sc[1][r]), fmaxf(sc[2][r], sc[3][r]));
                    bool needA = (mx[0] > m[rg][0] + 8.f) || (mx[1] > m[rg][1] + 8.f) ||
                                 (mx[2] > m[rg][2] + 8.f) || (mx[3] > m[rg][3] + 8.f);
                    if (__any(needA)) {
#pragma unroll
                        for (int r = 0; r < 4; ++r) {
                            float t2 = mx[r];
                            t2 = fmaxf(t2, __shfl_xor(t2, 1));
                            t2 = fmaxf(t2, __shfl_xor(t2, 2));
                            t2 = fmaxf(t2, __shfl_xor(t2, 4));
                            t2 = fmaxf(t2, __shfl_xor(t2, 8));
                            float mn = fmaxf(m[rg][r], t2);
                            float alpha = __expf(m[rg][r] - mn);
                            m[rg][r] = mn;
                            lsum[rg][r] *= alpha;
#pragma unroll
                            for (int dt = 0; dt < 4; ++dt) of[rg][dt][r] *= alpha;
                        }
                    }
#pragma unroll
                    for (int r = 0; r < 4; ++r) {
                        float p0 = __expf(sc[0][r] - m[rg][r]);
                        float p1 = __expf(sc[1][r] - m[rg][r]);
                        float p2 = __expf(sc[2][r] - m[rg][r]);
                        float p3 = __expf(sc[3][r] - m[rg][r]);
                        lsum[rg][r] += (p0 + p1) + (p2 + p3);
                        int prow = (lg * 4 + r) * 72;
                        mypb[prow + lr]      = f2bf(p0);
                        mypb[prow + 16 + lr] = f2bf(p1);
                        mypb[prow + 32 + lr] = f2bf(p2);
                        mypb[prow + 48 + lr] = f2bf(p3);
                    }

                    // ---- PV
#pragma unroll
                    for (int ks = 0; ks < 2; ++ks) {
                        bf16x8 pa = *(const bf16x8*)(mypb + lr * 72 + ks * 32 + 8 * lg);
#pragma unroll
                        for (int dt = 0; dt < 4; ++dt) {
                            int row = dt * 16 + lr;
                            bf16x8 vf = *(const bf16x8*)&Vb[row][((ks * 4 + lg) ^ (row & 7)) * 8];
                            of[rg][dt] = __builtin_amdgcn_mfma_f32_16x16x32_bf16(pa, vf, of[rg][dt], 0, 0, 0);
                        }
                    }
                }
            }

            if (i + 1 < nt) {
                __syncthreads();                 // all waves done reading Kb/Vb
                WRITE();                          // next tile regs -> LDS
                if (i + 2 < nt) ISSUE(s + (i + 2) * NSPLIT);
                __syncthreads();                 // writes visible
            }
        }
    }
#undef ISSUE
#undef WRITE

    // epilogue: cross-lane lsum reduce + partial writes (64-row-tile indexing)
#pragma unroll
    for (int rg = 0; rg < 2; ++rg) {
#pragma unroll
        for (int r = 0; r < 4; ++r) {
            float ps = lsum[rg][r];
            ps += __shfl_xor(ps, 1);
            ps += __shfl_xor(ps, 2);
            ps += __shfl_xor(ps, 4);
            ps += __shfl_xor(ps, 8);
            lsum[rg][r] = ps;
        }
        int qt64 = qt * 2 + rg;
        short* myo  = po + (((size_t)b * 64 + qt64) * NSPLIT + s) * 4096;
        float* myml = ml + (((size_t)b * 64 + qt64) * NSPLIT + s) * 128;
#pragma unroll
        for (int r = 0; r < 4; ++r) {
            int row = w * 16 + lg * 4 + r;
#pragma unroll
            for (int dt = 0; dt < 4; ++dt) myo[row * 64 + dt * 16 + lr] = f2bf(of[rg][dt][r]);
            if (lr == 0) { myml[row] = m[rg][r]; myml[64 + row] = lsum[rg][r]; }
        }
    }
}

// ---------------- Kernel 3: merge the 8 kv-split partials (po bf16)
__global__ __launch_bounds__(256) void merge_kernel(const short* __restrict__ po,
                                                    const float* __restrict__ ml,
                                                    float* __restrict__ out)
{
    int qt = blockIdx.x;
    int b  = blockIdx.y;
    int row = threadIdx.x >> 2;
    int cg  = threadIdx.x & 3;

    size_t mlbase = ((size_t)b * 64 + qt) * NSPLIT * 128;
    float mm[NSPLIT], llv[NSPLIT];
#pragma unroll
    for (int s = 0; s < NSPLIT; ++s) {
        mm[s]  = ml[mlbase + s * 128 + row];
        llv[s] = ml[mlbase + s * 128 + 64 + row];
    }
    float M = -INFINITY;
#pragma unroll
    for (int s = 0; s < NSPLIT; ++s) M = fmaxf(M, mm[s]);
    float e[NSPLIT], den = 0.f;
#pragma unroll
    for (int s = 0; s < NSPLIT; ++s) { e[s] = __expf(mm[s] - M); den += e[s] * llv[s]; }
    float inv = 1.0f / den;

    size_t pbase = ((size_t)b * 64 + qt) * NSPLIT * 4096;
#pragma unroll
    for (int jj = 0; jj < 2; ++jj) {
        int col = cg * 16 + jj * 8;
        float acc8[8];
#pragma unroll
        for (int e2 = 0; e2 < 8; ++e2) acc8[e2] = 0.f;
#pragma unroll
        for (int s = 0; s < NSPLIT; ++s) {
            bf16x8 v = *(const bf16x8*)(po + pbase + s * 4096 + row * 64 + col);
#pragma unroll
            for (int e2 = 0; e2 < 8; ++e2) acc8[e2] += e[s] * bf2f(v[e2]);
        }
        float* orow = out + ((size_t)b * TT + qt * 64 + row) * DK + col;
#pragma unroll
        for (int e2 = 0; e2 < 8; ++e2) orow[e2] = acc8[e2] * inv;
    }
}

extern "C" void kernel_launch(void* const* d_in, const int* in_sizes, int n_in,
                              void* d_out, int out_size, void* d_ws, size_t ws_size,
                              hipStream_t stream) {
    const float* x     = (const float*)d_in[0];
    const float* freqs = (const float*)d_in[1];
    const float* Wq    = (const float*)d_in[2];
    const float* Wk    = (const float*)d_in[3];
    const float* Wv    = (const float*)d_in[4];
    float* out = (float*)d_out;

    char* ws = (char*)d_ws;
    short* Wt  = (short*)ws;                          // 384 KB
    short* qb  = (short*)(ws + 393216);               // 2 MB
    short* kb  = (short*)(ws + 2490368);              // 2 MB
    short* vtb = (short*)(ws + 4587520);              // 2 MB
    short* po  = (short*)(ws + 6684672);              // 16 MB partial O (bf16)
    float* ml  = (float*)(ws + 23461888);             // 1 MB partial m/l

    hipLaunchKernelGGL(wt_kernel, dim3(768), dim3(256), 0, stream, Wq, Wk, Wv, Wt);
    hipLaunchKernelGGL(proj_rope, dim3(768), dim3(256), 0, stream, x, freqs, Wt, qb, kb, vtb);
    hipLaunchKernelGGL(attn_kernel, dim3(32, BB, NSPLIT), dim3(256), 0, stream, qb, kb, vtb, po, ml);
    hipLaunchKernelGGL(merge_kernel, dim3(64, BB), dim3(256), 0, stream, po, ml, out);
}

// Round 14
// 69.113 us; speedup vs baseline: 1.0225x; 1.0225x over previous
//
#include <hip/hip_runtime.h>
#include <hip/hip_bf16.h>

#define BB 4
#define TT 4096
#define DM 1024
#define DK 64
#define NSPLIT 8

using f32x4  = __attribute__((ext_vector_type(4))) float;
using bf16x8 = __attribute__((ext_vector_type(8))) short;

__device__ __forceinline__ short f2bf(float f) {
    __hip_bfloat16 h = __float2bfloat16(f);
    return __builtin_bit_cast(short, h);
}
__device__ __forceinline__ float bf2f(short s) {
    unsigned int u = ((unsigned int)(unsigned short)s) << 16;
    return __builtin_bit_cast(float, u);
}

// ---------------- Kernel 0: pack Wq|Wk|Wv (f32 [1024][64]) -> Wt bf16 [192][1024]
__global__ __launch_bounds__(256) void wt_kernel(const float* __restrict__ Wq,
                                                 const float* __restrict__ Wk,
                                                 const float* __restrict__ Wv,
                                                 short* __restrict__ Wt) {
    int idx = blockIdx.x * 256 + threadIdx.x;
    if (idx >= 192 * 1024) return;
    int n = idx >> 10;
    int m = idx & 1023;
    const float* W = (n < 64) ? Wq : (n < 128) ? Wk : Wv;
    int c = n & 63;
    Wt[idx] = f2bf(W[m * 64 + c]);
}

// ---------------- Kernel 1: QKV projection GEMM (BM=64, 256 thr, bf16 LDS both sides)
// q is pre-scaled by 1/8 (folded attention scale).
__global__ __launch_bounds__(256, 4) void proj_rope(const float* __restrict__ x,
                                                    const float* __restrict__ freqs,
                                                    const short* __restrict__ Wt,
                                                    short* __restrict__ q,
                                                    short* __restrict__ k,
                                                    short* __restrict__ vt)
{
    __shared__ short As[2][4096];    // [64 rows][8 units of 16B], unit-XOR-swizzled
    __shared__ short Bs[2][4096];

    int t  = threadIdx.x;
    int w  = t >> 6;
    int l  = t & 63;
    int lr = l & 15;
    int lg = (l >> 4) & 3;
    int bx = blockIdx.x;
    int mt = (bx & 7) * 32 + (bx >> 3) / 3;   // trio-per-XCD
    int nh = (bx >> 3) % 3;                   // 0=q, 1=k, 2=v
    int m0 = mt * 64;

    int arow = t >> 2;
    int au2  = (t & 3) * 2;
    int aswz = arow & 7;
    const float* gA = x  + (size_t)(m0 + arow) * DM + au2 * 8;
    const short* gB = Wt + (size_t)(nh * 64 + arow) * DM + au2 * 8;

    f32x4 ar[4]; bf16x8 br[2];

#define LOADG(c_) do { int kk = (c_) << 6;                     \
        ar[0] = *(const f32x4*)(gA + kk);                      \
        ar[1] = *(const f32x4*)(gA + kk + 4);                  \
        ar[2] = *(const f32x4*)(gA + kk + 8);                  \
        ar[3] = *(const f32x4*)(gA + kk + 12);                 \
        br[0] = *(const bf16x8*)(gB + kk);                     \
        br[1] = *(const bf16x8*)(gB + kk + 8);                 \
    } while (0)

#define WRITELDS(buf_) do {                                                    \
        int sa = arow * 64;                                                    \
        bf16x8 a0_, a1_;                                                       \
        for (int j_ = 0; j_ < 4; ++j_) {                                       \
            a0_[j_] = f2bf(ar[0][j_]); a0_[4 + j_] = f2bf(ar[1][j_]);          \
            a1_[j_] = f2bf(ar[2][j_]); a1_[4 + j_] = f2bf(ar[3][j_]);          \
        }                                                                      \
        *(bf16x8*)&As[buf_][sa + (((au2    ) ^ aswz) << 3)] = a0_;             \
        *(bf16x8*)&As[buf_][sa + (((au2 + 1) ^ aswz) << 3)] = a1_;             \
        *(bf16x8*)&Bs[buf_][sa + (((au2    ) ^ aswz) << 3)] = br[0];           \
        *(bf16x8*)&Bs[buf_][sa + (((au2 + 1) ^ aswz) << 3)] = br[1];           \
    } while (0)

    f32x4 acc[4];
#pragma unroll
    for (int i = 0; i < 4; ++i) acc[i] = (f32x4){0.f, 0.f, 0.f, 0.f};

    LOADG(0); WRITELDS(0); LOADG(1);
    __syncthreads();

    int cur = 0;
    int r7 = lr & 7;
    int amrow = (w * 16 + lr) * 64;
    for (int ch = 0; ch < 16; ++ch) {
#pragma unroll
        for (int s = 0; s < 2; ++s) {
            int u0 = s * 4 + lg;
            bf16x8 af = *(const bf16x8*)&As[cur][amrow + ((u0 ^ r7) << 3)];
#pragma unroll
            for (int nt = 0; nt < 4; ++nt) {
                bf16x8 bfr = *(const bf16x8*)&Bs[cur][(nt * 16 + lr) * 64 + ((u0 ^ r7) << 3)];
                acc[nt] = __builtin_amdgcn_mfma_f32_16x16x32_bf16(af, bfr, acc[nt], 0, 0, 0);
            }
        }
        if (ch + 1 < 16) {
            WRITELDS(cur ^ 1);
            if (ch + 2 < 16) LOADG(ch + 2);
            __syncthreads();
            cur ^= 1;
        }
    }
#undef LOADG
#undef WRITELDS

    __syncthreads();

    if (nh == 2) {
        short* vs = &Bs[0][0];
#pragma unroll
        for (int r = 0; r < 4; ++r)
#pragma unroll
            for (int nt = 0; nt < 4; ++nt)
                vs[(w * 16 + lg * 4 + r) * 64 + nt * 16 + lr] = f2bf(acc[nt][r]);
        __syncthreads();
        int b   = mt >> 6;
        int tt0 = (mt & 63) * 64;
        int c   = t >> 2;
        int toff = (t & 3) * 16;
        bf16x8 v0, v1;
#pragma unroll
        for (int j = 0; j < 8; ++j) {
            v0[j] = vs[(toff + j) * 64 + c];
            v1[j] = vs[(toff + 8 + j) * 64 + c];
        }
        short* dstv = vt + ((size_t)b * DK + c) * TT + tt0 + toff;
        *(bf16x8*)dstv = v0;
        *(bf16x8*)(dstv + 8) = v1;
    } else {
        short* dst = nh ? k : q;
        float postscale = nh ? 1.0f : 0.125f;      // fold S-scale into q
#pragma unroll
        for (int r = 0; r < 4; ++r) {
            int tg = m0 + w * 16 + lg * 4 + r;
            int tt = tg & (TT - 1);
#pragma unroll
            for (int nt = 0; nt < 4; ++nt) {
                int c = nt * 16 + lr;
                float e = acc[nt][r];
                float p = __shfl_xor(e, 1);
                float2 f = ((const float2*)freqs)[(size_t)tt * 32 + (c >> 1)];
                float sgn = (c & 1) ? f.y : -f.y;
                dst[(size_t)tg * DK + c] = f2bf((e * f.x + p * sgn) * postscale);
            }
        }
    }
}

// ---------------- Kernel 2: causal flash attention (R8 structure, 5-waves/EU ask)
// Single-buffer 25.6 KB LDS, 1-deep reg prefetch, diagonal-only mask, gated
// defer-max, per-lane lsum deferral. (256,5): VGPR cap 102 vs total need ~84
// -> expect no spills and 5 blocks/CU (20 waves). If WRITE_SIZE balloons, revert.
__global__ __launch_bounds__(256, 5) void attn_kernel(const short* __restrict__ q,
                                                      const short* __restrict__ k,
                                                      const short* __restrict__ vt,
                                                      short* __restrict__ po,
                                                      float* __restrict__ ml)
{
    __shared__ short Kb[64][64];
    __shared__ short Vb[64][64];
    __shared__ short pbuf[4][16][72];

    int w  = threadIdx.x >> 6;
    int l  = threadIdx.x & 63;
    int lr = l & 15;
    int lg = l >> 4;
    int b  = blockIdx.y;
    int s  = blockIdx.z;
    int qt = 63 - blockIdx.x;
    int q0 = qt * 64;
    int qrow_wave = q0 + w * 16;

    const short* qB = q  + (size_t)b * TT * DK;
    const short* kB = k  + (size_t)b * TT * DK;
    const short* vB = vt + (size_t)b * DK * TT;

    bf16x8 qf0 = *(const bf16x8*)(qB + (size_t)(qrow_wave + lr) * DK + 8 * lg);
    bf16x8 qf1 = *(const bf16x8*)(qB + (size_t)(qrow_wave + lr) * DK + 32 + 8 * lg);

    f32x4 of[4];
#pragma unroll
    for (int i = 0; i < 4; ++i) of[i] = (f32x4){0.f, 0.f, 0.f, 0.f};
    float m[4], lsum[4];
#pragma unroll
    for (int r = 0; r < 4; ++r) { m[r] = -INFINITY; lsum[r] = 0.f; }

    int nt = (qt >= s) ? ((qt - s + NSPLIT) >> 3) : 0;

    int srow = threadIdx.x >> 2;
    int u0   = (threadIdx.x & 3) * 2;
    int p0s  = ((u0) ^ (srow & 7)) * 8;
    int p1s  = ((u0 + 1) ^ (srow & 7)) * 8;

    bf16x8 kr0, kr1, vr0, vr1;
    short* mypb = &pbuf[w][0][0];

#define ISSUE(tile_) do {                                                        \
        int kv0_ = (tile_) << 6;                                                 \
        const short* gk_ = kB + (size_t)(kv0_ + srow) * DK + (u0 * 8);           \
        const short* gv_ = vB + (size_t)srow * TT + kv0_ + (u0 * 8);             \
        kr0 = *(const bf16x8*)gk_; kr1 = *(const bf16x8*)(gk_ + 8);              \
        vr0 = *(const bf16x8*)gv_; vr1 = *(const bf16x8*)(gv_ + 8);              \
    } while (0)

#define WRITE() do {                                                             \
        *(bf16x8*)&Kb[srow][p0s] = kr0;                                         \
        *(bf16x8*)&Kb[srow][p1s] = kr1;                                         \
        *(bf16x8*)&Vb[srow][p0s] = vr0;                                         \
        *(bf16x8*)&Vb[srow][p1s] = vr1;                                         \
    } while (0)

    if (nt > 0) {
        ISSUE(s); WRITE();
        if (nt > 1) ISSUE(s + NSPLIT);
        __syncthreads();
        for (int i = 0; i < nt; ++i) {
            int kv0 = (s + i * NSPLIT) << 6;

            // ---- QK^T
            f32x4 sc[4];
#pragma unroll
            for (int c = 0; c < 4; ++c) sc[c] = (f32x4){0.f, 0.f, 0.f, 0.f};
#pragma unroll
            for (int c = 0; c < 4; ++c) {
                int row = c * 16 + lr;
                bf16x8 kf0 = *(const bf16x8*)&Kb[row][((lg) ^ (row & 7)) * 8];
                bf16x8 kf1 = *(const bf16x8*)&Kb[row][((4 + lg) ^ (row & 7)) * 8];
                sc[c] = __builtin_amdgcn_mfma_f32_16x16x32_bf16(qf0, kf0, sc[c], 0, 0, 0);
                sc[c] = __builtin_amdgcn_mfma_f32_16x16x32_bf16(qf1, kf1, sc[c], 0, 0, 0);
            }

            // ---- mask only on the diagonal tile
            if (kv0 == q0) {
#pragma unroll
                for (int r = 0; r < 4; ++r) {
                    int qg = qrow_wave + lg * 4 + r;
#pragma unroll
                    for (int c = 0; c < 4; ++c)
                        sc[c][r] = (kv0 + c * 16 + lr <= qg) ? sc[c][r] : -INFINITY;
                }
            }

            // ---- local per-lane row max; gate the expensive path on it
            float mx[4];
#pragma unroll
            for (int r = 0; r < 4; ++r)
                mx[r] = fmaxf(fmaxf(sc[0][r], sc[1][r]), fmaxf(sc[2][r], sc[3][r]));
            bool needA = (mx[0] > m[0] + 8.f) || (mx[1] > m[1] + 8.f) ||
                         (mx[2] > m[2] + 8.f) || (mx[3] > m[3] + 8.f);
            if (__any(needA)) {
#pragma unroll
                for (int r = 0; r < 4; ++r) {
                    float t2 = mx[r];
                    t2 = fmaxf(t2, __shfl_xor(t2, 1));
                    t2 = fmaxf(t2, __shfl_xor(t2, 2));
                    t2 = fmaxf(t2, __shfl_xor(t2, 4));
                    t2 = fmaxf(t2, __shfl_xor(t2, 8));
                    float mn = fmaxf(m[r], t2);
                    float alpha = __expf(m[r] - mn);   // uniform across 16-lane group
                    m[r] = mn;
                    lsum[r] *= alpha;                  // per-lane partial scaled exactly
#pragma unroll
                    for (int dt = 0; dt < 4; ++dt) of[dt][r] *= alpha;
                }
            }
#pragma unroll
            for (int r = 0; r < 4; ++r) {
                float p0 = __expf(sc[0][r] - m[r]);
                float p1 = __expf(sc[1][r] - m[r]);
                float p2 = __expf(sc[2][r] - m[r]);
                float p3 = __expf(sc[3][r] - m[r]);
                lsum[r] += (p0 + p1) + (p2 + p3);      // reduce deferred to epilogue
                int prow = (lg * 4 + r) * 72;
                mypb[prow + lr]      = f2bf(p0);
                mypb[prow + 16 + lr] = f2bf(p1);
                mypb[prow + 32 + lr] = f2bf(p2);
                mypb[prow + 48 + lr] = f2bf(p3);
            }

            // ---- PV
#pragma unroll
            for (int ks = 0; ks < 2; ++ks) {
                bf16x8 pa = *(const bf16x8*)(mypb + lr * 72 + ks * 32 + 8 * lg);
#pragma unroll
                for (int dt = 0; dt < 4; ++dt) {
                    int row = dt * 16 + lr;
                    bf16x8 vf = *(const bf16x8*)&Vb[row][((ks * 4 + lg) ^ (row & 7)) * 8];
                    of[dt] = __builtin_amdgcn_mfma_f32_16x16x32_bf16(pa, vf, of[dt], 0, 0, 0);
                }
            }

            if (i + 1 < nt) {
                __syncthreads();                 // all waves done reading Kb/Vb
                WRITE();                          // next tile regs -> LDS
                if (i + 2 < nt) ISSUE(s + (i + 2) * NSPLIT);
                __syncthreads();                 // writes visible
            }
        }
    }
#undef ISSUE
#undef WRITE

    // epilogue: one cross-lane lsum reduce
#pragma unroll
    for (int r = 0; r < 4; ++r) {
        float ps = lsum[r];
        ps += __shfl_xor(ps, 1);
        ps += __shfl_xor(ps, 2);
        ps += __shfl_xor(ps, 4);
        ps += __shfl_xor(ps, 8);
        lsum[r] = ps;
    }

    short* myo  = po + (((size_t)b * 64 + qt) * NSPLIT + s) * 4096;
    float* myml = ml + (((size_t)b * 64 + qt) * NSPLIT + s) * 128;
#pragma unroll
    for (int r = 0; r < 4; ++r) {
        int row = w * 16 + lg * 4 + r;
#pragma unroll
        for (int dt = 0; dt < 4; ++dt) myo[row * 64 + dt * 16 + lr] = f2bf(of[dt][r]);
        if (lr == 0) { myml[row] = m[r]; myml[64 + row] = lsum[r]; }
    }
}

// ---------------- Kernel 3: merge the 8 kv-split partials (po bf16)
__global__ __launch_bounds__(256) void merge_kernel(const short* __restrict__ po,
                                                    const float* __restrict__ ml,
                                                    float* __restrict__ out)
{
    int qt = blockIdx.x;
    int b  = blockIdx.y;
    int row = threadIdx.x >> 2;
    int cg  = threadIdx.x & 3;

    size_t mlbase = ((size_t)b * 64 + qt) * NSPLIT * 128;
    float mm[NSPLIT], llv[NSPLIT];
#pragma unroll
    for (int s = 0; s < NSPLIT; ++s) {
        mm[s]  = ml[mlbase + s * 128 + row];
        llv[s] = ml[mlbase + s * 128 + 64 + row];
    }
    float M = -INFINITY;
#pragma unroll
    for (int s = 0; s < NSPLIT; ++s) M = fmaxf(M, mm[s]);
    float e[NSPLIT], den = 0.f;
#pragma unroll
    for (int s = 0; s < NSPLIT; ++s) { e[s] = __expf(mm[s] - M); den += e[s] * llv[s]; }
    float inv = 1.0f / den;

    size_t pbase = ((size_t)b * 64 + qt) * NSPLIT * 4096;
#pragma unroll
    for (int jj = 0; jj < 2; ++jj) {
        int col = cg * 16 + jj * 8;
        float acc8[8];
#pragma unroll
        for (int e2 = 0; e2 < 8; ++e2) acc8[e2] = 0.f;
#pragma unroll
        for (int s = 0; s < NSPLIT; ++s) {
            bf16x8 v = *(const bf16x8*)(po + pbase + s * 4096 + row * 64 + col);
#pragma unroll
            for (int e2 = 0; e2 < 8; ++e2) acc8[e2] += e[s] * bf2f(v[e2]);
        }
        float* orow = out + ((size_t)b * TT + qt * 64 + row) * DK + col;
#pragma unroll
        for (int e2 = 0; e2 < 8; ++e2) orow[e2] = acc8[e2] * inv;
    }
}

extern "C" void kernel_launch(void* const* d_in, const int* in_sizes, int n_in,
                              void* d_out, int out_size, void* d_ws, size_t ws_size,
                              hipStream_t stream) {
    const float* x     = (const float*)d_in[0];
    const float* freqs = (const float*)d_in[1];
    const float* Wq    = (const float*)d_in[2];
    const float* Wk    = (const float*)d_in[3];
    const float* Wv    = (const float*)d_in[4];
    float* out = (float*)d_out;

    char* ws = (char*)d_ws;
    short* Wt  = (short*)ws;                          // 384 KB
    short* qb  = (short*)(ws + 393216);               // 2 MB
    short* kb  = (short*)(ws + 2490368);              // 2 MB
    short* vtb = (short*)(ws + 4587520);              // 2 MB
    short* po  = (short*)(ws + 6684672);              // 16 MB partial O (bf16)
    float* ml  = (float*)(ws + 23461888);             // 1 MB partial m/l

    hipLaunchKernelGGL(wt_kernel, dim3(768), dim3(256), 0, stream, Wq, Wk, Wv, Wt);
    hipLaunchKernelGGL(proj_rope, dim3(768), dim3(256), 0, stream, x, freqs, Wt, qb, kb, vtb);
    hipLaunchKernelGGL(attn_kernel, dim3(64, BB, NSPLIT), dim3(256), 0, stream, qb, kb, vtb, po, ml);
    hipLaunchKernelGGL(merge_kernel, dim3(64, BB), dim3(256), 0, stream, po, ml, out);
}

// Round 15
// 66.480 us; speedup vs baseline: 1.0630x; 1.0396x over previous
//
#include <hip/hip_runtime.h>
#include <hip/hip_bf16.h>

#define BB 4
#define TT 4096
#define DM 1024
#define DK 64
#define NSPLIT 8

using f32x4  = __attribute__((ext_vector_type(4))) float;
using bf16x8 = __attribute__((ext_vector_type(8))) short;

__device__ __forceinline__ short f2bf(float f) {
    __hip_bfloat16 h = __float2bfloat16(f);
    return __builtin_bit_cast(short, h);
}
__device__ __forceinline__ float bf2f(short s) {
    unsigned int u = ((unsigned int)(unsigned short)s) << 16;
    return __builtin_bit_cast(float, u);
}

// ---------------- Kernel 0: pack Wq|Wk|Wv (f32 [1024][64]) -> Wt bf16 [192][1024]
__global__ __launch_bounds__(256) void wt_kernel(const float* __restrict__ Wq,
                                                 const float* __restrict__ Wk,
                                                 const float* __restrict__ Wv,
                                                 short* __restrict__ Wt) {
    int idx = blockIdx.x * 256 + threadIdx.x;
    if (idx >= 192 * 1024) return;
    int n = idx >> 10;
    int m = idx & 1023;
    const float* W = (n < 64) ? Wq : (n < 128) ? Wk : Wv;
    int c = n & 63;
    Wt[idx] = f2bf(W[m * 64 + c]);
}

// ---------------- Kernel 1: QKV projection GEMM (BM=64, 256 thr, bf16 LDS both sides)
// (256,5): 5 blocks/CU (LDS 5*32KB = 160KB exact; reg need ~65 < 102 cap).
// q is pre-scaled by 1/8 (folded attention scale).
__global__ __launch_bounds__(256, 5) void proj_rope(const float* __restrict__ x,
                                                    const float* __restrict__ freqs,
                                                    const short* __restrict__ Wt,
                                                    short* __restrict__ q,
                                                    short* __restrict__ k,
                                                    short* __restrict__ vt)
{
    __shared__ short As[2][4096];    // [64 rows][8 units of 16B], unit-XOR-swizzled
    __shared__ short Bs[2][4096];

    int t  = threadIdx.x;
    int w  = t >> 6;
    int l  = t & 63;
    int lr = l & 15;
    int lg = (l >> 4) & 3;
    int bx = blockIdx.x;
    int mt = (bx & 7) * 32 + (bx >> 3) / 3;   // trio-per-XCD
    int nh = (bx >> 3) % 3;                   // 0=q, 1=k, 2=v
    int m0 = mt * 64;

    int arow = t >> 2;
    int au2  = (t & 3) * 2;
    int aswz = arow & 7;
    const float* gA = x  + (size_t)(m0 + arow) * DM + au2 * 8;
    const short* gB = Wt + (size_t)(nh * 64 + arow) * DM + au2 * 8;

    f32x4 ar[4]; bf16x8 br[2];

#define LOADG(c_) do { int kk = (c_) << 6;                     \
        ar[0] = *(const f32x4*)(gA + kk);                      \
        ar[1] = *(const f32x4*)(gA + kk + 4);                  \
        ar[2] = *(const f32x4*)(gA + kk + 8);                  \
        ar[3] = *(const f32x4*)(gA + kk + 12);                 \
        br[0] = *(const bf16x8*)(gB + kk);                     \
        br[1] = *(const bf16x8*)(gB + kk + 8);                 \
    } while (0)

#define WRITELDS(buf_) do {                                                    \
        int sa = arow * 64;                                                    \
        bf16x8 a0_, a1_;                                                       \
        for (int j_ = 0; j_ < 4; ++j_) {                                       \
            a0_[j_] = f2bf(ar[0][j_]); a0_[4 + j_] = f2bf(ar[1][j_]);          \
            a1_[j_] = f2bf(ar[2][j_]); a1_[4 + j_] = f2bf(ar[3][j_]);          \
        }                                                                      \
        *(bf16x8*)&As[buf_][sa + (((au2    ) ^ aswz) << 3)] = a0_;             \
        *(bf16x8*)&As[buf_][sa + (((au2 + 1) ^ aswz) << 3)] = a1_;             \
        *(bf16x8*)&Bs[buf_][sa + (((au2    ) ^ aswz) << 3)] = br[0];           \
        *(bf16x8*)&Bs[buf_][sa + (((au2 + 1) ^ aswz) << 3)] = br[1];           \
    } while (0)

    f32x4 acc[4];
#pragma unroll
    for (int i = 0; i < 4; ++i) acc[i] = (f32x4){0.f, 0.f, 0.f, 0.f};

    LOADG(0); WRITELDS(0); LOADG(1);
    __syncthreads();

    int cur = 0;
    int r7 = lr & 7;
    int amrow = (w * 16 + lr) * 64;
    for (int ch = 0; ch < 16; ++ch) {
#pragma unroll
        for (int s = 0; s < 2; ++s) {
            int u0 = s * 4 + lg;
            bf16x8 af = *(const bf16x8*)&As[cur][amrow + ((u0 ^ r7) << 3)];
#pragma unroll
            for (int nt = 0; nt < 4; ++nt) {
                bf16x8 bfr = *(const bf16x8*)&Bs[cur][(nt * 16 + lr) * 64 + ((u0 ^ r7) << 3)];
                acc[nt] = __builtin_amdgcn_mfma_f32_16x16x32_bf16(af, bfr, acc[nt], 0, 0, 0);
            }
        }
        if (ch + 1 < 16) {
            WRITELDS(cur ^ 1);
            if (ch + 2 < 16) LOADG(ch + 2);
            __syncthreads();
            cur ^= 1;
        }
    }
#undef LOADG
#undef WRITELDS

    __syncthreads();

    if (nh == 2) {
        short* vs = &Bs[0][0];
#pragma unroll
        for (int r = 0; r < 4; ++r)
#pragma unroll
            for (int nt = 0; nt < 4; ++nt)
                vs[(w * 16 + lg * 4 + r) * 64 + nt * 16 + lr] = f2bf(acc[nt][r]);
        __syncthreads();
        int b   = mt >> 6;
        int tt0 = (mt & 63) * 64;
        int c   = t >> 2;
        int toff = (t & 3) * 16;
        bf16x8 v0, v1;
#pragma unroll
        for (int j = 0; j < 8; ++j) {
            v0[j] = vs[(toff + j) * 64 + c];
            v1[j] = vs[(toff + 8 + j) * 64 + c];
        }
        short* dstv = vt + ((size_t)b * DK + c) * TT + tt0 + toff;
        *(bf16x8*)dstv = v0;
        *(bf16x8*)(dstv + 8) = v1;
    } else {
        short* dst = nh ? k : q;
        float postscale = nh ? 1.0f : 0.125f;      // fold S-scale into q
#pragma unroll
        for (int r = 0; r < 4; ++r) {
            int tg = m0 + w * 16 + lg * 4 + r;
            int tt = tg & (TT - 1);
#pragma unroll
            for (int nt = 0; nt < 4; ++nt) {
                int c = nt * 16 + lr;
                float e = acc[nt][r];
                float p = __shfl_xor(e, 1);
                float2 f = ((const float2*)freqs)[(size_t)tt * 32 + (c >> 1)];
                float sgn = (c & 1) ? f.y : -f.y;
                dst[(size_t)tg * DK + c] = f2bf((e * f.x + p * sgn) * postscale);
            }
        }
    }
}

// ---------------- Kernel 2: causal flash attention (R8 config — best measured, (256,4))
// Single-buffer 25.6 KB LDS, 1-deep reg prefetch, diagonal-only mask, gated
// defer-max, per-lane lsum deferral. (256,4) confirmed optimal: (256,5/6/8) all spill.
__global__ __launch_bounds__(256, 4) void attn_kernel(const short* __restrict__ q,
                                                      const short* __restrict__ k,
                                                      const short* __restrict__ vt,
                                                      short* __restrict__ po,
                                                      float* __restrict__ ml)
{
    __shared__ short Kb[64][64];
    __shared__ short Vb[64][64];
    __shared__ short pbuf[4][16][72];

    int w  = threadIdx.x >> 6;
    int l  = threadIdx.x & 63;
    int lr = l & 15;
    int lg = l >> 4;
    int b  = blockIdx.y;
    int s  = blockIdx.z;
    int qt = 63 - blockIdx.x;
    int q0 = qt * 64;
    int qrow_wave = q0 + w * 16;

    const short* qB = q  + (size_t)b * TT * DK;
    const short* kB = k  + (size_t)b * TT * DK;
    const short* vB = vt + (size_t)b * DK * TT;

    bf16x8 qf0 = *(const bf16x8*)(qB + (size_t)(qrow_wave + lr) * DK + 8 * lg);
    bf16x8 qf1 = *(const bf16x8*)(qB + (size_t)(qrow_wave + lr) * DK + 32 + 8 * lg);

    f32x4 of[4];
#pragma unroll
    for (int i = 0; i < 4; ++i) of[i] = (f32x4){0.f, 0.f, 0.f, 0.f};
    float m[4], lsum[4];
#pragma unroll
    for (int r = 0; r < 4; ++r) { m[r] = -INFINITY; lsum[r] = 0.f; }

    int nt = (qt >= s) ? ((qt - s + NSPLIT) >> 3) : 0;

    int srow = threadIdx.x >> 2;
    int u0   = (threadIdx.x & 3) * 2;
    int p0s  = ((u0) ^ (srow & 7)) * 8;
    int p1s  = ((u0 + 1) ^ (srow & 7)) * 8;

    bf16x8 kr0, kr1, vr0, vr1;
    short* mypb = &pbuf[w][0][0];

#define ISSUE(tile_) do {                                                        \
        int kv0_ = (tile_) << 6;                                                 \
        const short* gk_ = kB + (size_t)(kv0_ + srow) * DK + (u0 * 8);           \
        const short* gv_ = vB + (size_t)srow * TT + kv0_ + (u0 * 8);             \
        kr0 = *(const bf16x8*)gk_; kr1 = *(const bf16x8*)(gk_ + 8);              \
        vr0 = *(const bf16x8*)gv_; vr1 = *(const bf16x8*)(gv_ + 8);              \
    } while (0)

#define WRITE() do {                                                             \
        *(bf16x8*)&Kb[srow][p0s] = kr0;                                         \
        *(bf16x8*)&Kb[srow][p1s] = kr1;                                         \
        *(bf16x8*)&Vb[srow][p0s] = vr0;                                         \
        *(bf16x8*)&Vb[srow][p1s] = vr1;                                         \
    } while (0)

    if (nt > 0) {
        ISSUE(s); WRITE();
        if (nt > 1) ISSUE(s + NSPLIT);
        __syncthreads();
        for (int i = 0; i < nt; ++i) {
            int kv0 = (s + i * NSPLIT) << 6;

            // ---- QK^T
            f32x4 sc[4];
#pragma unroll
            for (int c = 0; c < 4; ++c) sc[c] = (f32x4){0.f, 0.f, 0.f, 0.f};
#pragma unroll
            for (int c = 0; c < 4; ++c) {
                int row = c * 16 + lr;
                bf16x8 kf0 = *(const bf16x8*)&Kb[row][((lg) ^ (row & 7)) * 8];
                bf16x8 kf1 = *(const bf16x8*)&Kb[row][((4 + lg) ^ (row & 7)) * 8];
                sc[c] = __builtin_amdgcn_mfma_f32_16x16x32_bf16(qf0, kf0, sc[c], 0, 0, 0);
                sc[c] = __builtin_amdgcn_mfma_f32_16x16x32_bf16(qf1, kf1, sc[c], 0, 0, 0);
            }

            // ---- mask only on the diagonal tile
            if (kv0 == q0) {
#pragma unroll
                for (int r = 0; r < 4; ++r) {
                    int qg = qrow_wave + lg * 4 + r;
#pragma unroll
                    for (int c = 0; c < 4; ++c)
                        sc[c][r] = (kv0 + c * 16 + lr <= qg) ? sc[c][r] : -INFINITY;
                }
            }

            // ---- local per-lane row max; gate the expensive path on it
            float mx[4];
#pragma unroll
            for (int r = 0; r < 4; ++r)
                mx[r] = fmaxf(fmaxf(sc[0][r], sc[1][r]), fmaxf(sc[2][r], sc[3][r]));
            bool needA = (mx[0] > m[0] + 8.f) || (mx[1] > m[1] + 8.f) ||
                         (mx[2] > m[2] + 8.f) || (mx[3] > m[3] + 8.f);
            if (__any(needA)) {
#pragma unroll
                for (int r = 0; r < 4; ++r) {
                    float t2 = mx[r];
                    t2 = fmaxf(t2, __shfl_xor(t2, 1));
                    t2 = fmaxf(t2, __shfl_xor(t2, 2));
                    t2 = fmaxf(t2, __shfl_xor(t2, 4));
                    t2 = fmaxf(t2, __shfl_xor(t2, 8));
                    float mn = fmaxf(m[r], t2);
                    float alpha = __expf(m[r] - mn);   // uniform across 16-lane group
                    m[r] = mn;
                    lsum[r] *= alpha;                  // per-lane partial scaled exactly
#pragma unroll
                    for (int dt = 0; dt < 4; ++dt) of[dt][r] *= alpha;
                }
            }
#pragma unroll
            for (int r = 0; r < 4; ++r) {
                float p0 = __expf(sc[0][r] - m[r]);
                float p1 = __expf(sc[1][r] - m[r]);
                float p2 = __expf(sc[2][r] - m[r]);
                float p3 = __expf(sc[3][r] - m[r]);
                lsum[r] += (p0 + p1) + (p2 + p3);      // reduce deferred to epilogue
                int prow = (lg * 4 + r) * 72;
                mypb[prow + lr]      = f2bf(p0);
                mypb[prow + 16 + lr] = f2bf(p1);
                mypb[prow + 32 + lr] = f2bf(p2);
                mypb[prow + 48 + lr] = f2bf(p3);
            }

            // ---- PV
#pragma unroll
            for (int ks = 0; ks < 2; ++ks) {
                bf16x8 pa = *(const bf16x8*)(mypb + lr * 72 + ks * 32 + 8 * lg);
#pragma unroll
                for (int dt = 0; dt < 4; ++dt) {
                    int row = dt * 16 + lr;
                    bf16x8 vf = *(const bf16x8*)&Vb[row][((ks * 4 + lg) ^ (row & 7)) * 8];
                    of[dt] = __builtin_amdgcn_mfma_f32_16x16x32_bf16(pa, vf, of[dt], 0, 0, 0);
                }
            }

            if (i + 1 < nt) {
                __syncthreads();                 // all waves done reading Kb/Vb
                WRITE();                          // next tile regs -> LDS
                if (i + 2 < nt) ISSUE(s + (i + 2) * NSPLIT);
                __syncthreads();                 // writes visible
            }
        }
    }
#undef ISSUE
#undef WRITE

    // epilogue: one cross-lane lsum reduce
#pragma unroll
    for (int r = 0; r < 4; ++r) {
        float ps = lsum[r];
        ps += __shfl_xor(ps, 1);
        ps += __shfl_xor(ps, 2);
        ps += __shfl_xor(ps, 4);
        ps += __shfl_xor(ps, 8);
        lsum[r] = ps;
    }

    short* myo  = po + (((size_t)b * 64 + qt) * NSPLIT + s) * 4096;
    float* myml = ml + (((size_t)b * 64 + qt) * NSPLIT + s) * 128;
#pragma unroll
    for (int r = 0; r < 4; ++r) {
        int row = w * 16 + lg * 4 + r;
#pragma unroll
        for (int dt = 0; dt < 4; ++dt) myo[row * 64 + dt * 16 + lr] = f2bf(of[dt][r]);
        if (lr == 0) { myml[row] = m[r]; myml[64 + row] = lsum[r]; }
    }
}

// ---------------- Kernel 3: merge the 8 kv-split partials (po bf16)
__global__ __launch_bounds__(256) void merge_kernel(const short* __restrict__ po,
                                                    const float* __restrict__ ml,
                                                    float* __restrict__ out)
{
    int qt = blockIdx.x;
    int b  = blockIdx.y;
    int row = threadIdx.x >> 2;
    int cg  = threadIdx.x & 3;

    size_t mlbase = ((size_t)b * 64 + qt) * NSPLIT * 128;
    float mm[NSPLIT], llv[NSPLIT];
#pragma unroll
    for (int s = 0; s < NSPLIT; ++s) {
        mm[s]  = ml[mlbase + s * 128 + row];
        llv[s] = ml[mlbase + s * 128 + 64 + row];
    }
    float M = -INFINITY;
#pragma unroll
    for (int s = 0; s < NSPLIT; ++s) M = fmaxf(M, mm[s]);
    float e[NSPLIT], den = 0.f;
#pragma unroll
    for (int s = 0; s < NSPLIT; ++s) { e[s] = __expf(mm[s] - M); den += e[s] * llv[s]; }
    float inv = 1.0f / den;

    size_t pbase = ((size_t)b * 64 + qt) * NSPLIT * 4096;
#pragma unroll
    for (int jj = 0; jj < 2; ++jj) {
        int col = cg * 16 + jj * 8;
        float acc8[8];
#pragma unroll
        for (int e2 = 0; e2 < 8; ++e2) acc8[e2] = 0.f;
#pragma unroll
        for (int s = 0; s < NSPLIT; ++s) {
            bf16x8 v = *(const bf16x8*)(po + pbase + s * 4096 + row * 64 + col);
#pragma unroll
            for (int e2 = 0; e2 < 8; ++e2) acc8[e2] += e[s] * bf2f(v[e2]);
        }
        float* orow = out + ((size_t)b * TT + qt * 64 + row) * DK + col;
#pragma unroll
        for (int e2 = 0; e2 < 8; ++e2) orow[e2] = acc8[e2] * inv;
    }
}

extern "C" void kernel_launch(void* const* d_in, const int* in_sizes, int n_in,
                              void* d_out, int out_size, void* d_ws, size_t ws_size,
                              hipStream_t stream) {
    const float* x     = (const float*)d_in[0];
    const float* freqs = (const float*)d_in[1];
    const float* Wq    = (const float*)d_in[2];
    const float* Wk    = (const float*)d_in[3];
    const float* Wv    = (const float*)d_in[4];
    float* out = (float*)d_out;

    char* ws = (char*)d_ws;
    short* Wt  = (short*)ws;                          // 384 KB
    short* qb  = (short*)(ws + 393216);               // 2 MB
    short* kb  = (short*)(ws + 2490368);              // 2 MB
    short* vtb = (short*)(ws + 4587520);              // 2 MB
    short* po  = (short*)(ws + 6684672);              // 16 MB partial O (bf16)
    float* ml  = (float*)(ws + 23461888);             // 1 MB partial m/l

    hipLaunchKernelGGL(wt_kernel, dim3(768), dim3(256), 0, stream, Wq, Wk, Wv, Wt);
    hipLaunchKernelGGL(proj_rope, dim3(768), dim3(256), 0, stream, x, freqs, Wt, qb, kb, vtb);
    hipLaunchKernelGGL(attn_kernel, dim3(64, BB, NSPLIT), dim3(256), 0, stream, qb, kb, vtb, po, ml);
    hipLaunchKernelGGL(merge_kernel, dim3(64, BB), dim3(256), 0, stream, po, ml, out);
}

// Round 16
// 65.664 us; speedup vs baseline: 1.0762x; 1.0124x over previous
//
#include <hip/hip_runtime.h>
#include <hip/hip_bf16.h>

#define BB 4
#define TT 4096
#define DM 1024
#define DK 64
#define NSPLIT 8

using f32x4  = __attribute__((ext_vector_type(4))) float;
using bf16x8 = __attribute__((ext_vector_type(8))) short;

__device__ __forceinline__ short f2bf(float f) {
    __hip_bfloat16 h = __float2bfloat16(f);
    return __builtin_bit_cast(short, h);
}
__device__ __forceinline__ float bf2f(short s) {
    unsigned int u = ((unsigned int)(unsigned short)s) << 16;
    return __builtin_bit_cast(float, u);
}

// ---------------- Kernel 0: pack Wq|Wk|Wv (f32 [1024][64]) -> Wt bf16 [192][1024]
__global__ __launch_bounds__(256) void wt_kernel(const float* __restrict__ Wq,
                                                 const float* __restrict__ Wk,
                                                 const float* __restrict__ Wv,
                                                 short* __restrict__ Wt) {
    int idx = blockIdx.x * 256 + threadIdx.x;
    if (idx >= 192 * 1024) return;
    int n = idx >> 10;
    int m = idx & 1023;
    const float* W = (n < 64) ? Wq : (n < 128) ? Wk : Wv;
    int c = n & 63;
    Wt[idx] = f2bf(W[m * 64 + c]);
}

// ---------------- Kernel 1: QKV projection GEMM, BM=32 (grid 1536 = 6 blocks/CU exact)
// 4 waves as 2x2 (16 rows x 32 cols each, acc[2]). bf16 LDS both sides, 24.6 KB.
// q is pre-scaled by 1/8 (folded attention scale).
__global__ __launch_bounds__(256, 6) void proj_rope(const float* __restrict__ x,
                                                    const float* __restrict__ freqs,
                                                    const short* __restrict__ Wt,
                                                    short* __restrict__ q,
                                                    short* __restrict__ k,
                                                    short* __restrict__ vt)
{
    __shared__ short As[2][2048];    // [32 rows][8 units of 16B], unit-XOR-swizzled
    __shared__ short Bs[2][4096];    // [64 rows][8 units]

    int t  = threadIdx.x;
    int w  = t >> 6;
    int l  = t & 63;
    int lr = l & 15;
    int lg = (l >> 4) & 3;
    int wr = w & 1;                  // row group (16 rows)
    int wc = w >> 1;                 // col group (2 n-tiles of 16)
    int bx = blockIdx.x;
    int mt = (bx & 7) * 64 + (bx >> 3) / 3;   // 0..511, trio {bx,bx+8,bx+16} same mt+XCD
    int nh = (bx >> 3) % 3;                   // 0=q, 1=k, 2=v
    int m0 = mt * 32;

    // staging geometry
    int arow = t >> 3, au = t & 7;            // A: 32 rows x 8 units (one bf16x8 each)
    int aswz = arow & 7;
    int brow = t >> 2, bu2 = (t & 3) * 2;     // B: 64 rows x 2 units each
    int bswz = brow & 7;
    const float* gA = x  + (size_t)(m0 + arow) * DM + au * 8;
    const short* gB = Wt + (size_t)(nh * 64 + brow) * DM + bu2 * 8;

    f32x4 ar[2]; bf16x8 br[2];

#define LOADG(c_) do { int kk = (c_) << 6;                     \
        ar[0] = *(const f32x4*)(gA + kk);                      \
        ar[1] = *(const f32x4*)(gA + kk + 4);                  \
        br[0] = *(const bf16x8*)(gB + kk);                     \
        br[1] = *(const bf16x8*)(gB + kk + 8);                 \
    } while (0)

#define WRITELDS(buf_) do {                                                    \
        bf16x8 a0_;                                                            \
        for (int j_ = 0; j_ < 4; ++j_) {                                       \
            a0_[j_] = f2bf(ar[0][j_]); a0_[4 + j_] = f2bf(ar[1][j_]);          \
        }                                                                      \
        *(bf16x8*)&As[buf_][arow * 64 + ((au ^ aswz) << 3)] = a0_;             \
        *(bf16x8*)&Bs[buf_][brow * 64 + (((bu2    ) ^ bswz) << 3)] = br[0];    \
        *(bf16x8*)&Bs[buf_][brow * 64 + (((bu2 + 1) ^ bswz) << 3)] = br[1];    \
    } while (0)

    f32x4 acc[2];
#pragma unroll
    for (int i = 0; i < 2; ++i) acc[i] = (f32x4){0.f, 0.f, 0.f, 0.f};

    LOADG(0); WRITELDS(0); LOADG(1);
    __syncthreads();

    int cur = 0;
    int r7 = lr & 7;
    int amrow = (wr * 16 + lr) * 64;
    for (int ch = 0; ch < 16; ++ch) {
#pragma unroll
        for (int s = 0; s < 2; ++s) {
            int u0 = s * 4 + lg;
            bf16x8 af = *(const bf16x8*)&As[cur][amrow + ((u0 ^ r7) << 3)];
#pragma unroll
            for (int ntl = 0; ntl < 2; ++ntl) {
                int row = (wc * 2 + ntl) * 16 + lr;
                bf16x8 bfr = *(const bf16x8*)&Bs[cur][row * 64 + ((u0 ^ r7) << 3)];
                acc[ntl] = __builtin_amdgcn_mfma_f32_16x16x32_bf16(af, bfr, acc[ntl], 0, 0, 0);
            }
        }
        if (ch + 1 < 16) {
            WRITELDS(cur ^ 1);
            if (ch + 2 < 16) LOADG(ch + 2);
            __syncthreads();
            cur ^= 1;
        }
    }
#undef LOADG
#undef WRITELDS

    __syncthreads();

    if (nh == 2) {
        // V: stage 32x64 bf16 tile, write vt[b][c][t] coalesced (bf16x8 along t)
        short* vs = &Bs[0][0];
#pragma unroll
        for (int r = 0; r < 4; ++r)
#pragma unroll
            for (int ntl = 0; ntl < 2; ++ntl)
                vs[(wr * 16 + lg * 4 + r) * 64 + (wc * 2 + ntl) * 16 + lr] = f2bf(acc[ntl][r]);
        __syncthreads();
        int b    = mt >> 7;                 // 128 tiles of 32 rows per batch
        int tt0  = (mt & 127) * 32;
        int c    = t >> 2;                  // 0..63
        int tgrp = t & 3;                   // 4 groups of 8 rows
        bf16x8 v0;
#pragma unroll
        for (int j = 0; j < 8; ++j) v0[j] = vs[(tgrp * 8 + j) * 64 + c];
        *(bf16x8*)(vt + ((size_t)b * DK + c) * TT + tt0 + tgrp * 8) = v0;
    } else {
        short* dst = nh ? k : q;
        float postscale = nh ? 1.0f : 0.125f;      // fold S-scale into q
#pragma unroll
        for (int r = 0; r < 4; ++r) {
            int tg = m0 + wr * 16 + lg * 4 + r;
            int tt = tg & (TT - 1);
#pragma unroll
            for (int ntl = 0; ntl < 2; ++ntl) {
                int c = (wc * 2 + ntl) * 16 + lr;
                float e = acc[ntl][r];
                float p = __shfl_xor(e, 1);
                float2 f = ((const float2*)freqs)[(size_t)tt * 32 + (c >> 1)];
                float sgn = (c & 1) ? f.y : -f.y;
                dst[(size_t)tg * DK + c] = f2bf((e * f.x + p * sgn) * postscale);
            }
        }
    }
}

// ---------------- Kernel 2: causal flash attention (R8 config — best measured, (256,4))
__global__ __launch_bounds__(256, 4) void attn_kernel(const short* __restrict__ q,
                                                      const short* __restrict__ k,
                                                      const short* __restrict__ vt,
                                                      short* __restrict__ po,
                                                      float* __restrict__ ml)
{
    __shared__ short Kb[64][64];
    __shared__ short Vb[64][64];
    __shared__ short pbuf[4][16][72];

    int w  = threadIdx.x >> 6;
    int l  = threadIdx.x & 63;
    int lr = l & 15;
    int lg = l >> 4;
    int b  = blockIdx.y;
    int s  = blockIdx.z;
    int qt = 63 - blockIdx.x;
    int q0 = qt * 64;
    int qrow_wave = q0 + w * 16;

    const short* qB = q  + (size_t)b * TT * DK;
    const short* kB = k  + (size_t)b * TT * DK;
    const short* vB = vt + (size_t)b * DK * TT;

    bf16x8 qf0 = *(const bf16x8*)(qB + (size_t)(qrow_wave + lr) * DK + 8 * lg);
    bf16x8 qf1 = *(const bf16x8*)(qB + (size_t)(qrow_wave + lr) * DK + 32 + 8 * lg);

    f32x4 of[4];
#pragma unroll
    for (int i = 0; i < 4; ++i) of[i] = (f32x4){0.f, 0.f, 0.f, 0.f};
    float m[4], lsum[4];
#pragma unroll
    for (int r = 0; r < 4; ++r) { m[r] = -INFINITY; lsum[r] = 0.f; }

    int nt = (qt >= s) ? ((qt - s + NSPLIT) >> 3) : 0;

    int srow = threadIdx.x >> 2;
    int u0   = (threadIdx.x & 3) * 2;
    int p0s  = ((u0) ^ (srow & 7)) * 8;
    int p1s  = ((u0 + 1) ^ (srow & 7)) * 8;

    bf16x8 kr0, kr1, vr0, vr1;
    short* mypb = &pbuf[w][0][0];

#define ISSUE(tile_) do {                                                        \
        int kv0_ = (tile_) << 6;                                                 \
        const short* gk_ = kB + (size_t)(kv0_ + srow) * DK + (u0 * 8);           \
        const short* gv_ = vB + (size_t)srow * TT + kv0_ + (u0 * 8);             \
        kr0 = *(const bf16x8*)gk_; kr1 = *(const bf16x8*)(gk_ + 8);              \
        vr0 = *(const bf16x8*)gv_; vr1 = *(const bf16x8*)(gv_ + 8);              \
    } while (0)

#define WRITE() do {                                                             \
        *(bf16x8*)&Kb[srow][p0s] = kr0;                                         \
        *(bf16x8*)&Kb[srow][p1s] = kr1;                                         \
        *(bf16x8*)&Vb[srow][p0s] = vr0;                                         \
        *(bf16x8*)&Vb[srow][p1s] = vr1;                                         \
    } while (0)

    if (nt > 0) {
        ISSUE(s); WRITE();
        if (nt > 1) ISSUE(s + NSPLIT);
        __syncthreads();
        for (int i = 0; i < nt; ++i) {
            int kv0 = (s + i * NSPLIT) << 6;

            // ---- QK^T
            f32x4 sc[4];
#pragma unroll
            for (int c = 0; c < 4; ++c) sc[c] = (f32x4){0.f, 0.f, 0.f, 0.f};
#pragma unroll
            for (int c = 0; c < 4; ++c) {
                int row = c * 16 + lr;
                bf16x8 kf0 = *(const bf16x8*)&Kb[row][((lg) ^ (row & 7)) * 8];
                bf16x8 kf1 = *(const bf16x8*)&Kb[row][((4 + lg) ^ (row & 7)) * 8];
                sc[c] = __builtin_amdgcn_mfma_f32_16x16x32_bf16(qf0, kf0, sc[c], 0, 0, 0);
                sc[c] = __builtin_amdgcn_mfma_f32_16x16x32_bf16(qf1, kf1, sc[c], 0, 0, 0);
            }

            // ---- mask only on the diagonal tile
            if (kv0 == q0) {
#pragma unroll
                for (int r = 0; r < 4; ++r) {
                    int qg = qrow_wave + lg * 4 + r;
#pragma unroll
                    for (int c = 0; c < 4; ++c)
                        sc[c][r] = (kv0 + c * 16 + lr <= qg) ? sc[c][r] : -INFINITY;
                }
            }

            // ---- local per-lane row max; gate the expensive path on it
            float mx[4];
#pragma unroll
            for (int r = 0; r < 4; ++r)
                mx[r] = fmaxf(fmaxf(sc[0][r], sc[1][r]), fmaxf(sc[2][r], sc[3][r]));
            bool needA = (mx[0] > m[0] + 8.f) || (mx[1] > m[1] + 8.f) ||
                         (mx[2] > m[2] + 8.f) || (mx[3] > m[3] + 8.f);
            if (__any(needA)) {
#pragma unroll
                for (int r = 0; r < 4; ++r) {
                    float t2 = mx[r];
                    t2 = fmaxf(t2, __shfl_xor(t2, 1));
                    t2 = fmaxf(t2, __shfl_xor(t2, 2));
                    t2 = fmaxf(t2, __shfl_xor(t2, 4));
                    t2 = fmaxf(t2, __shfl_xor(t2, 8));
                    float mn = fmaxf(m[r], t2);
                    float alpha = __expf(m[r] - mn);   // uniform across 16-lane group
                    m[r] = mn;
                    lsum[r] *= alpha;                  // per-lane partial scaled exactly
#pragma unroll
                    for (int dt = 0; dt < 4; ++dt) of[dt][r] *= alpha;
                }
            }
#pragma unroll
            for (int r = 0; r < 4; ++r) {
                float p0 = __expf(sc[0][r] - m[r]);
                float p1 = __expf(sc[1][r] - m[r]);
                float p2 = __expf(sc[2][r] - m[r]);
                float p3 = __expf(sc[3][r] - m[r]);
                lsum[r] += (p0 + p1) + (p2 + p3);      // reduce deferred to epilogue
                int prow = (lg * 4 + r) * 72;
                mypb[prow + lr]      = f2bf(p0);
                mypb[prow + 16 + lr] = f2bf(p1);
                mypb[prow + 32 + lr] = f2bf(p2);
                mypb[prow + 48 + lr] = f2bf(p3);
            }

            // ---- PV
#pragma unroll
            for (int ks = 0; ks < 2; ++ks) {
                bf16x8 pa = *(const bf16x8*)(mypb + lr * 72 + ks * 32 + 8 * lg);
#pragma unroll
                for (int dt = 0; dt < 4; ++dt) {
                    int row = dt * 16 + lr;
                    bf16x8 vf = *(const bf16x8*)&Vb[row][((ks * 4 + lg) ^ (row & 7)) * 8];
                    of[dt] = __builtin_amdgcn_mfma_f32_16x16x32_bf16(pa, vf, of[dt], 0, 0, 0);
                }
            }

            if (i + 1 < nt) {
                __syncthreads();                 // all waves done reading Kb/Vb
                WRITE();                          // next tile regs -> LDS
                if (i + 2 < nt) ISSUE(s + (i + 2) * NSPLIT);
                __syncthreads();                 // writes visible
            }
        }
    }
#undef ISSUE
#undef WRITE

    // epilogue: one cross-lane lsum reduce
#pragma unroll
    for (int r = 0; r < 4; ++r) {
        float ps = lsum[r];
        ps += __shfl_xor(ps, 1);
        ps += __shfl_xor(ps, 2);
        ps += __shfl_xor(ps, 4);
        ps += __shfl_xor(ps, 8);
        lsum[r] = ps;
    }

    short* myo  = po + (((size_t)b * 64 + qt) * NSPLIT + s) * 4096;
    float* myml = ml + (((size_t)b * 64 + qt) * NSPLIT + s) * 128;
#pragma unroll
    for (int r = 0; r < 4; ++r) {
        int row = w * 16 + lg * 4 + r;
#pragma unroll
        for (int dt = 0; dt < 4; ++dt) myo[row * 64 + dt * 16 + lr] = f2bf(of[dt][r]);
        if (lr == 0) { myml[row] = m[r]; myml[64 + row] = lsum[r]; }
    }
}

// ---------------- Kernel 3: merge the 8 kv-split partials (po bf16)
__global__ __launch_bounds__(256) void merge_kernel(const short* __restrict__ po,
                                                    const float* __restrict__ ml,
                                                    float* __restrict__ out)
{
    int qt = blockIdx.x;
    int b  = blockIdx.y;
    int row = threadIdx.x >> 2;
    int cg  = threadIdx.x & 3;

    size_t mlbase = ((size_t)b * 64 + qt) * NSPLIT * 128;
    float mm[NSPLIT], llv[NSPLIT];
#pragma unroll
    for (int s = 0; s < NSPLIT; ++s) {
        mm[s]  = ml[mlbase + s * 128 + row];
        llv[s] = ml[mlbase + s * 128 + 64 + row];
    }
    float M = -INFINITY;
#pragma unroll
    for (int s = 0; s < NSPLIT; ++s) M = fmaxf(M, mm[s]);
    float e[NSPLIT], den = 0.f;
#pragma unroll
    for (int s = 0; s < NSPLIT; ++s) { e[s] = __expf(mm[s] - M); den += e[s] * llv[s]; }
    float inv = 1.0f / den;

    size_t pbase = ((size_t)b * 64 + qt) * NSPLIT * 4096;
#pragma unroll
    for (int jj = 0; jj < 2; ++jj) {
        int col = cg * 16 + jj * 8;
        float acc8[8];
#pragma unroll
        for (int e2 = 0; e2 < 8; ++e2) acc8[e2] = 0.f;
#pragma unroll
        for (int s = 0; s < NSPLIT; ++s) {
            bf16x8 v = *(const bf16x8*)(po + pbase + s * 4096 + row * 64 + col);
#pragma unroll
            for (int e2 = 0; e2 < 8; ++e2) acc8[e2] += e[s] * bf2f(v[e2]);
        }
        float* orow = out + ((size_t)b * TT + qt * 64 + row) * DK + col;
#pragma unroll
        for (int e2 = 0; e2 < 8; ++e2) orow[e2] = acc8[e2] * inv;
    }
}

extern "C" void kernel_launch(void* const* d_in, const int* in_sizes, int n_in,
                              void* d_out, int out_size, void* d_ws, size_t ws_size,
                              hipStream_t stream) {
    const float* x     = (const float*)d_in[0];
    const float* freqs = (const float*)d_in[1];
    const float* Wq    = (const float*)d_in[2];
    const float* Wk    = (const float*)d_in[3];
    const float* Wv    = (const float*)d_in[4];
    float* out = (float*)d_out;

    char* ws = (char*)d_ws;
    short* Wt  = (short*)ws;                          // 384 KB
    short* qb  = (short*)(ws + 393216);               // 2 MB
    short* kb  = (short*)(ws + 2490368);              // 2 MB
    short* vtb = (short*)(ws + 4587520);              // 2 MB
    short* po  = (short*)(ws + 6684672);              // 16 MB partial O (bf16)
    float* ml  = (float*)(ws + 23461888);             // 1 MB partial m/l

    hipLaunchKernelGGL(wt_kernel, dim3(768), dim3(256), 0, stream, Wq, Wk, Wv, Wt);
    hipLaunchKernelGGL(proj_rope, dim3(1536), dim3(256), 0, stream, x, freqs, Wt, qb, kb, vtb);
    hipLaunchKernelGGL(attn_kernel, dim3(64, BB, NSPLIT), dim3(256), 0, stream, qb, kb, vtb, po, ml);
    hipLaunchKernelGGL(merge_kernel, dim3(64, BB), dim3(256), 0, stream, po, ml, out);
}

// Round 17
// 65.185 us; speedup vs baseline: 1.0841x; 1.0074x over previous
//
#include <hip/hip_runtime.h>
#include <hip/hip_bf16.h>

#define BB 4
#define TT 4096
#define DM 1024
#define DK 64
#define NSPLIT 8

using f32x4  = __attribute__((ext_vector_type(4))) float;
using bf16x8 = __attribute__((ext_vector_type(8))) short;

__device__ __forceinline__ short f2bf(float f) {
    __hip_bfloat16 h = __float2bfloat16(f);
    return __builtin_bit_cast(short, h);
}
__device__ __forceinline__ float bf2f(short s) {
    unsigned int u = ((unsigned int)(unsigned short)s) << 16;
    return __builtin_bit_cast(float, u);
}

// ---------------- Kernel 0: pack Wq|Wk|Wv (f32 [1024][64]) -> Wt bf16 [192][1024]
__global__ __launch_bounds__(256) void wt_kernel(const float* __restrict__ Wq,
                                                 const float* __restrict__ Wk,
                                                 const float* __restrict__ Wv,
                                                 short* __restrict__ Wt) {
    int idx = blockIdx.x * 256 + threadIdx.x;
    if (idx >= 192 * 1024) return;
    int n = idx >> 10;
    int m = idx & 1023;
    const float* W = (n < 64) ? Wq : (n < 128) ? Wk : Wv;
    int c = n & 63;
    Wt[idx] = f2bf(W[m * 64 + c]);
}

// ---------------- Kernel 1: QKV projection GEMM — R5-era f32-As config (measured ~23 us)
// As f32 dbuf (32 KB) + Bs bf16 dbuf (16 KB), (256,3), 768 blocks, trio-XCD.
// f2bf conversion happens in the MFMA loop (latency-covered), NOT in staging.
// q is pre-scaled by 1/8 (folded attention scale).
__global__ __launch_bounds__(256, 3) void proj_rope(const float* __restrict__ x,
                                                    const float* __restrict__ freqs,
                                                    const short* __restrict__ Wt,
                                                    short* __restrict__ q,
                                                    short* __restrict__ k,
                                                    short* __restrict__ vt)
{
    __shared__ float As[2][4096];
    __shared__ short Bs[2][4096];

    int t  = threadIdx.x;
    int w  = t >> 6;
    int l  = t & 63;
    int lr = l & 15;
    int lg = (l >> 4) & 3;
    int bx = blockIdx.x;
    int mt = (bx & 7) * 32 + (bx >> 3) / 3;
    int nh = (bx >> 3) % 3;
    int m0 = mt * 64;

    int arow = t >> 2, au = (t & 3) * 4;
    int brow = t >> 2, bu = (t & 3) * 2;
    const float* gA = x  + (size_t)(m0 + arow) * DM + au * 4;
    const short* gB = Wt + (size_t)(nh * 64 + brow) * DM + bu * 8;
    int aswz = arow & 7, bswz = brow & 7;

    f32x4 ar[4]; bf16x8 br[2];

#define LOADG(c_) do { int kk = (c_) << 6;                     \
        ar[0] = *(const f32x4*)(gA + kk);                      \
        ar[1] = *(const f32x4*)(gA + kk + 4);                  \
        ar[2] = *(const f32x4*)(gA + kk + 8);                  \
        ar[3] = *(const f32x4*)(gA + kk + 12);                 \
        br[0] = *(const bf16x8*)(gB + kk);                     \
        br[1] = *(const bf16x8*)(gB + kk + 8);                 \
    } while (0)

#define WRITELDS(buf_) do {                                                    \
        int sa = arow * 64;                                                    \
        *(f32x4*)&As[buf_][sa + (((au + 0) ^ aswz) << 2)] = ar[0];             \
        *(f32x4*)&As[buf_][sa + (((au + 1) ^ aswz) << 2)] = ar[1];             \
        *(f32x4*)&As[buf_][sa + (((au + 2) ^ aswz) << 2)] = ar[2];             \
        *(f32x4*)&As[buf_][sa + (((au + 3) ^ aswz) << 2)] = ar[3];             \
        int sb = brow * 64;                                                    \
        *(bf16x8*)&Bs[buf_][sb + (((bu + 0) ^ bswz) << 3)] = br[0];            \
        *(bf16x8*)&Bs[buf_][sb + (((bu + 1) ^ bswz) << 3)] = br[1];            \
    } while (0)

    f32x4 acc[4];
#pragma unroll
    for (int i = 0; i < 4; ++i) acc[i] = (f32x4){0.f, 0.f, 0.f, 0.f};

    LOADG(0); WRITELDS(0); LOADG(1);
    __syncthreads();

    int cur = 0;
    int r7 = lr & 7;
    int amrow = (w * 16 + lr) * 64;
    for (int ch = 0; ch < 16; ++ch) {
#pragma unroll
        for (int s = 0; s < 2; ++s) {
            int u0 = s * 8 + lg * 2;
            f32x4 a0 = *(const f32x4*)&As[cur][amrow + (((u0    ) ^ r7) << 2)];
            f32x4 a1 = *(const f32x4*)&As[cur][amrow + (((u0 + 1) ^ r7) << 2)];
            bf16x8 af;
#pragma unroll
            for (int j = 0; j < 4; ++j) { af[j] = f2bf(a0[j]); af[4 + j] = f2bf(a1[j]); }
            int ub = s * 4 + lg;
#pragma unroll
            for (int nt = 0; nt < 4; ++nt) {
                bf16x8 bfr = *(const bf16x8*)&Bs[cur][(nt * 16 + lr) * 64 + ((ub ^ r7) << 3)];
                acc[nt] = __builtin_amdgcn_mfma_f32_16x16x32_bf16(af, bfr, acc[nt], 0, 0, 0);
            }
        }
        if (ch + 1 < 16) {
            WRITELDS(cur ^ 1);
            if (ch + 2 < 16) LOADG(ch + 2);
            __syncthreads();
            cur ^= 1;
        }
    }
#undef LOADG
#undef WRITELDS

    __syncthreads();

    if (nh == 2) {
        short* vs = &Bs[0][0];
#pragma unroll
        for (int r = 0; r < 4; ++r)
#pragma unroll
            for (int nt = 0; nt < 4; ++nt)
                vs[(w * 16 + lg * 4 + r) * 64 + nt * 16 + lr] = f2bf(acc[nt][r]);
        __syncthreads();
        int b   = mt >> 6;
        int tt0 = (mt & 63) * 64;
        int c   = t >> 2;
        int toff = (t & 3) * 16;
        bf16x8 v0, v1;
#pragma unroll
        for (int j = 0; j < 8; ++j) {
            v0[j] = vs[(toff + j) * 64 + c];
            v1[j] = vs[(toff + 8 + j) * 64 + c];
        }
        short* dstv = vt + ((size_t)b * DK + c) * TT + tt0 + toff;
        *(bf16x8*)dstv = v0;
        *(bf16x8*)(dstv + 8) = v1;
    } else {
        short* dst = nh ? k : q;
        float postscale = nh ? 1.0f : 0.125f;      // fold S-scale into q
#pragma unroll
        for (int r = 0; r < 4; ++r) {
            int tg = m0 + w * 16 + lg * 4 + r;
            int tt = tg & (TT - 1);
#pragma unroll
            for (int nt = 0; nt < 4; ++nt) {
                int c = nt * 16 + lr;
                float e = acc[nt][r];
                float p = __shfl_xor(e, 1);
                float2 f = ((const float2*)freqs)[(size_t)tt * 32 + (c >> 1)];
                float sgn = (c & 1) ? f.y : -f.y;
                dst[(size_t)tg * DK + c] = f2bf((e * f.x + p * sgn) * postscale);
            }
        }
    }
}

// ---------------- Kernel 2: causal flash attention (R8 config — best measured, (256,4))
__global__ __launch_bounds__(256, 4) void attn_kernel(const short* __restrict__ q,
                                                      const short* __restrict__ k,
                                                      const short* __restrict__ vt,
                                                      short* __restrict__ po,
                                                      float* __restrict__ ml)
{
    __shared__ short Kb[64][64];
    __shared__ short Vb[64][64];
    __shared__ short pbuf[4][16][72];

    int w  = threadIdx.x >> 6;
    int l  = threadIdx.x & 63;
    int lr = l & 15;
    int lg = l >> 4;
    int b  = blockIdx.y;
    int s  = blockIdx.z;
    int qt = 63 - blockIdx.x;
    int q0 = qt * 64;
    int qrow_wave = q0 + w * 16;

    const short* qB = q  + (size_t)b * TT * DK;
    const short* kB = k  + (size_t)b * TT * DK;
    const short* vB = vt + (size_t)b * DK * TT;

    bf16x8 qf0 = *(const bf16x8*)(qB + (size_t)(qrow_wave + lr) * DK + 8 * lg);
    bf16x8 qf1 = *(const bf16x8*)(qB + (size_t)(qrow_wave + lr) * DK + 32 + 8 * lg);

    f32x4 of[4];
#pragma unroll
    for (int i = 0; i < 4; ++i) of[i] = (f32x4){0.f, 0.f, 0.f, 0.f};
    float m[4], lsum[4];
#pragma unroll
    for (int r = 0; r < 4; ++r) { m[r] = -INFINITY; lsum[r] = 0.f; }

    int nt = (qt >= s) ? ((qt - s + NSPLIT) >> 3) : 0;

    int srow = threadIdx.x >> 2;
    int u0   = (threadIdx.x & 3) * 2;
    int p0s  = ((u0) ^ (srow & 7)) * 8;
    int p1s  = ((u0 + 1) ^ (srow & 7)) * 8;

    bf16x8 kr0, kr1, vr0, vr1;
    short* mypb = &pbuf[w][0][0];

#define ISSUE(tile_) do {                                                        \
        int kv0_ = (tile_) << 6;                                                 \
        const short* gk_ = kB + (size_t)(kv0_ + srow) * DK + (u0 * 8);           \
        const short* gv_ = vB + (size_t)srow * TT + kv0_ + (u0 * 8);             \
        kr0 = *(const bf16x8*)gk_; kr1 = *(const bf16x8*)(gk_ + 8);              \
        vr0 = *(const bf16x8*)gv_; vr1 = *(const bf16x8*)(gv_ + 8);              \
    } while (0)

#define WRITE() do {                                                             \
        *(bf16x8*)&Kb[srow][p0s] = kr0;                                         \
        *(bf16x8*)&Kb[srow][p1s] = kr1;                                         \
        *(bf16x8*)&Vb[srow][p0s] = vr0;                                         \
        *(bf16x8*)&Vb[srow][p1s] = vr1;                                         \
    } while (0)

    if (nt > 0) {
        ISSUE(s); WRITE();
        if (nt > 1) ISSUE(s + NSPLIT);
        __syncthreads();
        for (int i = 0; i < nt; ++i) {
            int kv0 = (s + i * NSPLIT) << 6;

            // ---- QK^T
            f32x4 sc[4];
#pragma unroll
            for (int c = 0; c < 4; ++c) sc[c] = (f32x4){0.f, 0.f, 0.f, 0.f};
#pragma unroll
            for (int c = 0; c < 4; ++c) {
                int row = c * 16 + lr;
                bf16x8 kf0 = *(const bf16x8*)&Kb[row][((lg) ^ (row & 7)) * 8];
                bf16x8 kf1 = *(const bf16x8*)&Kb[row][((4 + lg) ^ (row & 7)) * 8];
                sc[c] = __builtin_amdgcn_mfma_f32_16x16x32_bf16(qf0, kf0, sc[c], 0, 0, 0);
                sc[c] = __builtin_amdgcn_mfma_f32_16x16x32_bf16(qf1, kf1, sc[c], 0, 0, 0);
            }

            // ---- mask only on the diagonal tile
            if (kv0 == q0) {
#pragma unroll
                for (int r = 0; r < 4; ++r) {
                    int qg = qrow_wave + lg * 4 + r;
#pragma unroll
                    for (int c = 0; c < 4; ++c)
                        sc[c][r] = (kv0 + c * 16 + lr <= qg) ? sc[c][r] : -INFINITY;
                }
            }

            // ---- local per-lane row max; gate the expensive path on it
            float mx[4];
#pragma unroll
            for (int r = 0; r < 4; ++r)
                mx[r] = fmaxf(fmaxf(sc[0][r], sc[1][r]), fmaxf(sc[2][r], sc[3][r]));
            bool needA = (mx[0] > m[0] + 8.f) || (mx[1] > m[1] + 8.f) ||
                         (mx[2] > m[2] + 8.f) || (mx[3] > m[3] + 8.f);
            if (__any(needA)) {
#pragma unroll
                for (int r = 0; r < 4; ++r) {
                    float t2 = mx[r];
                    t2 = fmaxf(t2, __shfl_xor(t2, 1));
                    t2 = fmaxf(t2, __shfl_xor(t2, 2));
                    t2 = fmaxf(t2, __shfl_xor(t2, 4));
                    t2 = fmaxf(t2, __shfl_xor(t2, 8));
                    float mn = fmaxf(m[r], t2);
                    float alpha = __expf(m[r] - mn);   // uniform across 16-lane group
                    m[r] = mn;
                    lsum[r] *= alpha;                  // per-lane partial scaled exactly
#pragma unroll
                    for (int dt = 0; dt < 4; ++dt) of[dt][r] *= alpha;
                }
            }
#pragma unroll
            for (int r = 0; r < 4; ++r) {
                float p0 = __expf(sc[0][r] - m[r]);
                float p1 = __expf(sc[1][r] - m[r]);
                float p2 = __expf(sc[2][r] - m[r]);
                float p3 = __expf(sc[3][r] - m[r]);
                lsum[r] += (p0 + p1) + (p2 + p3);      // reduce deferred to epilogue
                int prow = (lg * 4 + r) * 72;
                mypb[prow + lr]      = f2bf(p0);
                mypb[prow + 16 + lr] = f2bf(p1);
                mypb[prow + 32 + lr] = f2bf(p2);
                mypb[prow + 48 + lr] = f2bf(p3);
            }

            // ---- PV
#pragma unroll
            for (int ks = 0; ks < 2; ++ks) {
                bf16x8 pa = *(const bf16x8*)(mypb + lr * 72 + ks * 32 + 8 * lg);
#pragma unroll
                for (int dt = 0; dt < 4; ++dt) {
                    int row = dt * 16 + lr;
                    bf16x8 vf = *(const bf16x8*)&Vb[row][((ks * 4 + lg) ^ (row & 7)) * 8];
                    of[dt] = __builtin_amdgcn_mfma_f32_16x16x32_bf16(pa, vf, of[dt], 0, 0, 0);
                }
            }

            if (i + 1 < nt) {
                __syncthreads();                 // all waves done reading Kb/Vb
                WRITE();                          // next tile regs -> LDS
                if (i + 2 < nt) ISSUE(s + (i + 2) * NSPLIT);
                __syncthreads();                 // writes visible
            }
        }
    }
#undef ISSUE
#undef WRITE

    // epilogue: one cross-lane lsum reduce
#pragma unroll
    for (int r = 0; r < 4; ++r) {
        float ps = lsum[r];
        ps += __shfl_xor(ps, 1);
        ps += __shfl_xor(ps, 2);
        ps += __shfl_xor(ps, 4);
        ps += __shfl_xor(ps, 8);
        lsum[r] = ps;
    }

    short* myo  = po + (((size_t)b * 64 + qt) * NSPLIT + s) * 4096;
    float* myml = ml + (((size_t)b * 64 + qt) * NSPLIT + s) * 128;
#pragma unroll
    for (int r = 0; r < 4; ++r) {
        int row = w * 16 + lg * 4 + r;
#pragma unroll
        for (int dt = 0; dt < 4; ++dt) myo[row * 64 + dt * 16 + lr] = f2bf(of[dt][r]);
        if (lr == 0) { myml[row] = m[r]; myml[64 + row] = lsum[r]; }
    }
}

// ---------------- Kernel 3: merge the 8 kv-split partials (po bf16)
__global__ __launch_bounds__(256) void merge_kernel(const short* __restrict__ po,
                                                    const float* __restrict__ ml,
                                                    float* __restrict__ out)
{
    int qt = blockIdx.x;
    int b  = blockIdx.y;
    int row = threadIdx.x >> 2;
    int cg  = threadIdx.x & 3;

    size_t mlbase = ((size_t)b * 64 + qt) * NSPLIT * 128;
    float mm[NSPLIT], llv[NSPLIT];
#pragma unroll
    for (int s = 0; s < NSPLIT; ++s) {
        mm[s]  = ml[mlbase + s * 128 + row];
        llv[s] = ml[mlbase + s * 128 + 64 + row];
    }
    float M = -INFINITY;
#pragma unroll
    for (int s = 0; s < NSPLIT; ++s) M = fmaxf(M, mm[s]);
    float e[NSPLIT], den = 0.f;
#pragma unroll
    for (int s = 0; s < NSPLIT; ++s) { e[s] = __expf(mm[s] - M); den += e[s] * llv[s]; }
    float inv = 1.0f / den;

    size_t pbase = ((size_t)b * 64 + qt) * NSPLIT * 4096;
#pragma unroll
    for (int jj = 0; jj < 2; ++jj) {
        int col = cg * 16 + jj * 8;
        float acc8[8];
#pragma unroll
        for (int e2 = 0; e2 < 8; ++e2) acc8[e2] = 0.f;
#pragma unroll
        for (int s = 0; s < NSPLIT; ++s) {
            bf16x8 v = *(const bf16x8*)(po + pbase + s * 4096 + row * 64 + col);
#pragma unroll
            for (int e2 = 0; e2 < 8; ++e2) acc8[e2] += e[s] * bf2f(v[e2]);
        }
        float* orow = out + ((size_t)b * TT + qt * 64 + row) * DK + col;
#pragma unroll
        for (int e2 = 0; e2 < 8; ++e2) orow[e2] = acc8[e2] * inv;
    }
}

extern "C" void kernel_launch(void* const* d_in, const int* in_sizes, int n_in,
                              void* d_out, int out_size, void* d_ws, size_t ws_size,
                              hipStream_t stream) {
    const float* x     = (const float*)d_in[0];
    const float* freqs = (const float*)d_in[1];
    const float* Wq    = (const float*)d_in[2];
    const float* Wk    = (const float*)d_in[3];
    const float* Wv    = (const float*)d_in[4];
    float* out = (float*)d_out;

    char* ws = (char*)d_ws;
    short* Wt  = (short*)ws;                          // 384 KB
    short* qb  = (short*)(ws + 393216);               // 2 MB
    short* kb  = (short*)(ws + 2490368);              // 2 MB
    short* vtb = (short*)(ws + 4587520);              // 2 MB
    short* po  = (short*)(ws + 6684672);              // 16 MB partial O (bf16)
    float* ml  = (float*)(ws + 23461888);             // 1 MB partial m/l

    hipLaunchKernelGGL(wt_kernel, dim3(768), dim3(256), 0, stream, Wq, Wk, Wv, Wt);
    hipLaunchKernelGGL(proj_rope, dim3(768), dim3(256), 0, stream, x, freqs, Wt, qb, kb, vtb);
    hipLaunchKernelGGL(attn_kernel, dim3(64, BB, NSPLIT), dim3(256), 0, stream, qb, kb, vtb, po, ml);
    hipLaunchKernelGGL(merge_kernel, dim3(64, BB), dim3(256), 0, stream, po, ml, out);
}

// Round 18
// 60.869 us; speedup vs baseline: 1.1610x; 1.0709x over previous
//
#include <hip/hip_runtime.h>
#include <hip/hip_bf16.h>

#define BB 4
#define TT 4096
#define DM 1024
#define DK 64
#define NSPLIT 8

using f32x4  = __attribute__((ext_vector_type(4))) float;
using bf16x8 = __attribute__((ext_vector_type(8))) short;

__device__ __forceinline__ short f2bf(float f) {
    __hip_bfloat16 h = __float2bfloat16(f);
    return __builtin_bit_cast(short, h);
}
__device__ __forceinline__ float bf2f(short s) {
    unsigned int u = ((unsigned int)(unsigned short)s) << 16;
    return __builtin_bit_cast(float, u);
}

// ---------------- Kernel 0: pack Wq|Wk|Wv (f32 [1024][64]) -> Wt bf16 [192][1024]
__global__ __launch_bounds__(256) void wt_kernel(const float* __restrict__ Wq,
                                                 const float* __restrict__ Wk,
                                                 const float* __restrict__ Wv,
                                                 short* __restrict__ Wt) {
    int idx = blockIdx.x * 256 + threadIdx.x;
    if (idx >= 192 * 1024) return;
    int n = idx >> 10;
    int m = idx & 1023;
    const float* W = (n < 64) ? Wq : (n < 128) ? Wk : Wv;
    int c = n & 63;
    Wt[idx] = f2bf(W[m * 64 + c]);
}

// ---------------- Kernel 1: FUSED QKV projection — one block computes q,k,v for a
// 32-row m-tile. 12 MFMA/wave per chunk (3x compute density vs nh-split) so the
// barrier interval covers HBM latency via ILP, not TLP. Grid 512 = 2 blocks/CU
// (LDS 56 KB). Waves: 2x2 (wr: 16 rows, wc: 32 cols), acc[3 nh][2 ntl].
// q is pre-scaled by 1/8 (folded attention scale).
__global__ __launch_bounds__(256, 2) void proj_rope(const float* __restrict__ x,
                                                    const float* __restrict__ freqs,
                                                    const short* __restrict__ Wt,
                                                    short* __restrict__ q,
                                                    short* __restrict__ k,
                                                    short* __restrict__ vt)
{
    __shared__ short As[2][2048];     // [32][64] bf16, unit-XOR-swizzled (4 KB each)
    __shared__ short Bs[2][12288];    // [192][64] bf16 (q|k|v rows), swizzled (24 KB each)

    int t  = threadIdx.x;
    int w  = t >> 6;
    int l  = t & 63;
    int lr = l & 15;
    int lg = (l >> 4) & 3;
    int wr = w & 1;                   // row group (16 rows)
    int wc = w >> 1;                  // col group (2 n-tiles of 16)
    int bx = blockIdx.x;
    int mt = (bx & 7) * 64 + (bx >> 3);   // 0..511, XCD-striped
    int m0 = mt * 32;

    // staging geometry
    int arow = t >> 3, au = t & 7;    // A: 32 rows x 8 units (8 cols f32 each)
    int aswz = arow & 7;
    int bswz = (t >> 3) & 7;          // B rows j*32+(t>>3): swz = (t>>3)&7 for all j
    const float* gA = x  + (size_t)(m0 + arow) * DM + au * 8;
    const short* gB = Wt + (size_t)(t >> 3) * DM + (t & 7) * 8;

    f32x4 ar[2]; bf16x8 br[6];

#define LOADG(c_) do { int kk = (c_) << 6;                                      \
        ar[0] = *(const f32x4*)(gA + kk);                                       \
        ar[1] = *(const f32x4*)(gA + kk + 4);                                   \
        _Pragma("unroll")                                                       \
        for (int j_ = 0; j_ < 6; ++j_)                                          \
            br[j_] = *(const bf16x8*)(gB + (size_t)(j_ * 32) * DM + kk);        \
    } while (0)

#define WRITELDS(buf_) do {                                                     \
        bf16x8 a0_;                                                             \
        _Pragma("unroll")                                                       \
        for (int j_ = 0; j_ < 4; ++j_) {                                        \
            a0_[j_] = f2bf(ar[0][j_]); a0_[4 + j_] = f2bf(ar[1][j_]);           \
        }                                                                       \
        *(bf16x8*)&As[buf_][arow * 64 + ((au ^ aswz) << 3)] = a0_;              \
        _Pragma("unroll")                                                       \
        for (int j_ = 0; j_ < 6; ++j_)                                          \
            *(bf16x8*)&Bs[buf_][(j_ * 32 + (t >> 3)) * 64 + (((t & 7) ^ bswz) << 3)] = br[j_]; \
    } while (0)

    f32x4 acc[6];                     // [nh][ntl]
#pragma unroll
    for (int i = 0; i < 6; ++i) acc[i] = (f32x4){0.f, 0.f, 0.f, 0.f};

    LOADG(0); WRITELDS(0); LOADG(1);
    __syncthreads();

    int cur = 0;
    int r7 = lr & 7;
    int amrow = (wr * 16 + lr) * 64;
    for (int ch = 0; ch < 16; ++ch) {
#pragma unroll
        for (int s = 0; s < 2; ++s) {
            int u0 = s * 4 + lg;
            bf16x8 af = *(const bf16x8*)&As[cur][amrow + ((u0 ^ r7) << 3)];
#pragma unroll
            for (int nh = 0; nh < 3; ++nh)
#pragma unroll
                for (int ntl = 0; ntl < 2; ++ntl) {
                    int row = nh * 64 + (wc * 2 + ntl) * 16 + lr;
                    bf16x8 bfr = *(const bf16x8*)&Bs[cur][row * 64 + ((u0 ^ r7) << 3)];
                    acc[nh * 2 + ntl] = __builtin_amdgcn_mfma_f32_16x16x32_bf16(af, bfr, acc[nh * 2 + ntl], 0, 0, 0);
                }
        }
        if (ch + 1 < 16) {
            WRITELDS(cur ^ 1);
            if (ch + 2 < 16) LOADG(ch + 2);
            __syncthreads();
            cur ^= 1;
        }
    }
#undef LOADG
#undef WRITELDS

    // ---- q, k epilogue with fused RoPE
#pragma unroll
    for (int nh = 0; nh < 2; ++nh) {
        short* dst = nh ? k : q;
        float postscale = nh ? 1.0f : 0.125f;
#pragma unroll
        for (int r = 0; r < 4; ++r) {
            int tg = m0 + wr * 16 + lg * 4 + r;
            int tt = tg & (TT - 1);
#pragma unroll
            for (int ntl = 0; ntl < 2; ++ntl) {
                int c = wc * 32 + ntl * 16 + lr;
                float e = acc[nh * 2 + ntl][r];
                float p = __shfl_xor(e, 1);
                float2 f = ((const float2*)freqs)[(size_t)tt * 32 + (c >> 1)];
                float sgn = (c & 1) ? f.y : -f.y;
                dst[(size_t)tg * DK + c] = f2bf((e * f.x + p * sgn) * postscale);
            }
        }
    }

    // ---- V epilogue: stage 32x64 in LDS (reuse As), write vt[b][c][t] coalesced
    __syncthreads();                  // all waves done with As/Bs reads
    short* vs = &As[0][0];
#pragma unroll
    for (int r = 0; r < 4; ++r)
#pragma unroll
        for (int ntl = 0; ntl < 2; ++ntl)
            vs[(wr * 16 + lg * 4 + r) * 64 + wc * 32 + ntl * 16 + lr] = f2bf(acc[4 + ntl][r]);
    __syncthreads();
    int b    = mt >> 7;               // 128 tiles of 32 rows per batch
    int tt0  = (mt & 127) * 32;
    int c    = t >> 2;                // 0..63
    int tgrp = t & 3;                 // 4 groups of 8 rows
    bf16x8 v0;
#pragma unroll
    for (int j = 0; j < 8; ++j) v0[j] = vs[(tgrp * 8 + j) * 64 + c];
    *(bf16x8*)(vt + ((size_t)b * DK + c) * TT + tt0 + tgrp * 8) = v0;
}

// ---------------- Kernel 2: causal flash attention (R8 config — best measured, (256,4))
__global__ __launch_bounds__(256, 4) void attn_kernel(const short* __restrict__ q,
                                                      const short* __restrict__ k,
                                                      const short* __restrict__ vt,
                                                      short* __restrict__ po,
                                                      float* __restrict__ ml)
{
    __shared__ short Kb[64][64];
    __shared__ short Vb[64][64];
    __shared__ short pbuf[4][16][72];

    int w  = threadIdx.x >> 6;
    int l  = threadIdx.x & 63;
    int lr = l & 15;
    int lg = l >> 4;
    int b  = blockIdx.y;
    int s  = blockIdx.z;
    int qt = 63 - blockIdx.x;
    int q0 = qt * 64;
    int qrow_wave = q0 + w * 16;

    const short* qB = q  + (size_t)b * TT * DK;
    const short* kB = k  + (size_t)b * TT * DK;
    const short* vB = vt + (size_t)b * DK * TT;

    bf16x8 qf0 = *(const bf16x8*)(qB + (size_t)(qrow_wave + lr) * DK + 8 * lg);
    bf16x8 qf1 = *(const bf16x8*)(qB + (size_t)(qrow_wave + lr) * DK + 32 + 8 * lg);

    f32x4 of[4];
#pragma unroll
    for (int i = 0; i < 4; ++i) of[i] = (f32x4){0.f, 0.f, 0.f, 0.f};
    float m[4], lsum[4];
#pragma unroll
    for (int r = 0; r < 4; ++r) { m[r] = -INFINITY; lsum[r] = 0.f; }

    int nt = (qt >= s) ? ((qt - s + NSPLIT) >> 3) : 0;

    int srow = threadIdx.x >> 2;
    int u0   = (threadIdx.x & 3) * 2;
    int p0s  = ((u0) ^ (srow & 7)) * 8;
    int p1s  = ((u0 + 1) ^ (srow & 7)) * 8;

    bf16x8 kr0, kr1, vr0, vr1;
    short* mypb = &pbuf[w][0][0];

#define ISSUE(tile_) do {                                                        \
        int kv0_ = (tile_) << 6;                                                 \
        const short* gk_ = kB + (size_t)(kv0_ + srow) * DK + (u0 * 8);           \
        const short* gv_ = vB + (size_t)srow * TT + kv0_ + (u0 * 8);             \
        kr0 = *(const bf16x8*)gk_; kr1 = *(const bf16x8*)(gk_ + 8);              \
        vr0 = *(const bf16x8*)gv_; vr1 = *(const bf16x8*)(gv_ + 8);              \
    } while (0)

#define WRITE() do {                                                             \
        *(bf16x8*)&Kb[srow][p0s] = kr0;                                         \
        *(bf16x8*)&Kb[srow][p1s] = kr1;                                         \
        *(bf16x8*)&Vb[srow][p0s] = vr0;                                         \
        *(bf16x8*)&Vb[srow][p1s] = vr1;                                         \
    } while (0)

    if (nt > 0) {
        ISSUE(s); WRITE();
        if (nt > 1) ISSUE(s + NSPLIT);
        __syncthreads();
        for (int i = 0; i < nt; ++i) {
            int kv0 = (s + i * NSPLIT) << 6;

            // ---- QK^T
            f32x4 sc[4];
#pragma unroll
            for (int c = 0; c < 4; ++c) sc[c] = (f32x4){0.f, 0.f, 0.f, 0.f};
#pragma unroll
            for (int c = 0; c < 4; ++c) {
                int row = c * 16 + lr;
                bf16x8 kf0 = *(const bf16x8*)&Kb[row][((lg) ^ (row & 7)) * 8];
                bf16x8 kf1 = *(const bf16x8*)&Kb[row][((4 + lg) ^ (row & 7)) * 8];
                sc[c] = __builtin_amdgcn_mfma_f32_16x16x32_bf16(qf0, kf0, sc[c], 0, 0, 0);
                sc[c] = __builtin_amdgcn_mfma_f32_16x16x32_bf16(qf1, kf1, sc[c], 0, 0, 0);
            }

            // ---- mask only on the diagonal tile
            if (kv0 == q0) {
#pragma unroll
                for (int r = 0; r < 4; ++r) {
                    int qg = qrow_wave + lg * 4 + r;
#pragma unroll
                    for (int c = 0; c < 4; ++c)
                        sc[c][r] = (kv0 + c * 16 + lr <= qg) ? sc[c][r] : -INFINITY;
                }
            }

            // ---- local per-lane row max; gate the expensive path on it
            float mx[4];
#pragma unroll
            for (int r = 0; r < 4; ++r)
                mx[r] = fmaxf(fmaxf(sc[0][r], sc[1][r]), fmaxf(sc[2][r], sc[3][r]));
            bool needA = (mx[0] > m[0] + 8.f) || (mx[1] > m[1] + 8.f) ||
                         (mx[2] > m[2] + 8.f) || (mx[3] > m[3] + 8.f);
            if (__any(needA)) {
#pragma unroll
                for (int r = 0; r < 4; ++r) {
                    float t2 = mx[r];
                    t2 = fmaxf(t2, __shfl_xor(t2, 1));
                    t2 = fmaxf(t2, __shfl_xor(t2, 2));
                    t2 = fmaxf(t2, __shfl_xor(t2, 4));
                    t2 = fmaxf(t2, __shfl_xor(t2, 8));
                    float mn = fmaxf(m[r], t2);
                    float alpha = __expf(m[r] - mn);   // uniform across 16-lane group
                    m[r] = mn;
                    lsum[r] *= alpha;                  // per-lane partial scaled exactly
#pragma unroll
                    for (int dt = 0; dt < 4; ++dt) of[dt][r] *= alpha;
                }
            }
#pragma unroll
            for (int r = 0; r < 4; ++r) {
                float p0 = __expf(sc[0][r] - m[r]);
                float p1 = __expf(sc[1][r] - m[r]);
                float p2 = __expf(sc[2][r] - m[r]);
                float p3 = __expf(sc[3][r] - m[r]);
                lsum[r] += (p0 + p1) + (p2 + p3);      // reduce deferred to epilogue
                int prow = (lg * 4 + r) * 72;
                mypb[prow + lr]      = f2bf(p0);
                mypb[prow + 16 + lr] = f2bf(p1);
                mypb[prow + 32 + lr] = f2bf(p2);
                mypb[prow + 48 + lr] = f2bf(p3);
            }

            // ---- PV
#pragma unroll
            for (int ks = 0; ks < 2; ++ks) {
                bf16x8 pa = *(const bf16x8*)(mypb + lr * 72 + ks * 32 + 8 * lg);
#pragma unroll
                for (int dt = 0; dt < 4; ++dt) {
                    int row = dt * 16 + lr;
                    bf16x8 vf = *(const bf16x8*)&Vb[row][((ks * 4 + lg) ^ (row & 7)) * 8];
                    of[dt] = __builtin_amdgcn_mfma_f32_16x16x32_bf16(pa, vf, of[dt], 0, 0, 0);
                }
            }

            if (i + 1 < nt) {
                __syncthreads();                 // all waves done reading Kb/Vb
                WRITE();                          // next tile regs -> LDS
                if (i + 2 < nt) ISSUE(s + (i + 2) * NSPLIT);
                __syncthreads();                 // writes visible
            }
        }
    }
#undef ISSUE
#undef WRITE

    // epilogue: one cross-lane lsum reduce
#pragma unroll
    for (int r = 0; r < 4; ++r) {
        float ps = lsum[r];
        ps += __shfl_xor(ps, 1);
        ps += __shfl_xor(ps, 2);
        ps += __shfl_xor(ps, 4);
        ps += __shfl_xor(ps, 8);
        lsum[r] = ps;
    }

    short* myo  = po + (((size_t)b * 64 + qt) * NSPLIT + s) * 4096;
    float* myml = ml + (((size_t)b * 64 + qt) * NSPLIT + s) * 128;
#pragma unroll
    for (int r = 0; r < 4; ++r) {
        int row = w * 16 + lg * 4 + r;
#pragma unroll
        for (int dt = 0; dt < 4; ++dt) myo[row * 64 + dt * 16 + lr] = f2bf(of[dt][r]);
        if (lr == 0) { myml[row] = m[r]; myml[64 + row] = lsum[r]; }
    }
}

// ---------------- Kernel 3: merge the 8 kv-split partials (po bf16)
__global__ __launch_bounds__(256) void merge_kernel(const short* __restrict__ po,
                                                    const float* __restrict__ ml,
                                                    float* __restrict__ out)
{
    int qt = blockIdx.x;
    int b  = blockIdx.y;
    int row = threadIdx.x >> 2;
    int cg  = threadIdx.x & 3;

    size_t mlbase = ((size_t)b * 64 + qt) * NSPLIT * 128;
    float mm[NSPLIT], llv[NSPLIT];
#pragma unroll
    for (int s = 0; s < NSPLIT; ++s) {
        mm[s]  = ml[mlbase + s * 128 + row];
        llv[s] = ml[mlbase + s * 128 + 64 + row];
    }
    float M = -INFINITY;
#pragma unroll
    for (int s = 0; s < NSPLIT; ++s) M = fmaxf(M, mm[s]);
    float e[NSPLIT], den = 0.f;
#pragma unroll
    for (int s = 0; s < NSPLIT; ++s) { e[s] = __expf(mm[s] - M); den += e[s] * llv[s]; }
    float inv = 1.0f / den;

    size_t pbase = ((size_t)b * 64 + qt) * NSPLIT * 4096;
#pragma unroll
    for (int jj = 0; jj < 2; ++jj) {
        int col = cg * 16 + jj * 8;
        float acc8[8];
#pragma unroll
        for (int e2 = 0; e2 < 8; ++e2) acc8[e2] = 0.f;
#pragma unroll
        for (int s = 0; s < NSPLIT; ++s) {
            bf16x8 v = *(const bf16x8*)(po + pbase + s * 4096 + row * 64 + col);
#pragma unroll
            for (int e2 = 0; e2 < 8; ++e2) acc8[e2] += e[s] * bf2f(v[e2]);
        }
        float* orow = out + ((size_t)b * TT + qt * 64 + row) * DK + col;
#pragma unroll
        for (int e2 = 0; e2 < 8; ++e2) orow[e2] = acc8[e2] * inv;
    }
}

extern "C" void kernel_launch(void* const* d_in, const int* in_sizes, int n_in,
                              void* d_out, int out_size, void* d_ws, size_t ws_size,
                              hipStream_t stream) {
    const float* x     = (const float*)d_in[0];
    const float* freqs = (const float*)d_in[1];
    const float* Wq    = (const float*)d_in[2];
    const float* Wk    = (const float*)d_in[3];
    const float* Wv    = (const float*)d_in[4];
    float* out = (float*)d_out;

    char* ws = (char*)d_ws;
    short* Wt  = (short*)ws;                          // 384 KB
    short* qb  = (short*)(ws + 393216);               // 2 MB
    short* kb  = (short*)(ws + 2490368);              // 2 MB
    short* vtb = (short*)(ws + 4587520);              // 2 MB
    short* po  = (short*)(ws + 6684672);              // 16 MB partial O (bf16)
    float* ml  = (float*)(ws + 23461888);             // 1 MB partial m/l

    hipLaunchKernelGGL(wt_kernel, dim3(768), dim3(256), 0, stream, Wq, Wk, Wv, Wt);
    hipLaunchKernelGGL(proj_rope, dim3(512), dim3(256), 0, stream, x, freqs, Wt, qb, kb, vtb);
    hipLaunchKernelGGL(attn_kernel, dim3(64, BB, NSPLIT), dim3(256), 0, stream, qb, kb, vtb, po, ml);
    hipLaunchKernelGGL(merge_kernel, dim3(64, BB), dim3(256), 0, stream, po, ml, out);
}